// Round 13
// baseline (127.229 us; speedup 1.0000x reference)
//
#include <hip/hip_runtime.h>
#include <math.h>

#define NW 4096
#define H 768
#define NC 49152
#define MSW 30
#define E 20
#define M 1024
#define CHUNK 64
#define NCH (NW / CHUNK)
#define NKT (H / 64)   // 12 K-tiles
// Pse: bf16 [NW][2048] (cols 0:1024 start-proj, 1024:2048 end-proj)
// Sbuf: f32 [NW][1024] attn-proj, overwritten in place by exp-weighted prefix:
//   Sbuf[r][m] = S[r+1][m] = sum_{i<=r} ewa[i]*Pattn[i][m]

typedef short bf16x8 __attribute__((ext_vector_type(8)));
typedef unsigned short u16x8 __attribute__((ext_vector_type(8)));
typedef float f32x4 __attribute__((ext_vector_type(4)));

__device__ __forceinline__ unsigned short f2bf(float x) {
    unsigned u = __float_as_uint(x);
    return (unsigned short)((u + 0x7fff + ((u >> 16) & 1)) >> 16);  // RNE
}
__device__ __forceinline__ float bf2f(unsigned short b) {
    return __uint_as_float(((unsigned)b) << 16);
}
__device__ __forceinline__ void gload16(const void* g, void* l) {
    __builtin_amdgcn_global_load_lds((const __attribute__((address_space(1))) void*)g,
                                     (__attribute__((address_space(3))) void*)l, 16, 0, 0);
}

// ===== merged preprocessing: [0,1024) doc_prep+hist-zero | [1024,3328) cvt_bt | [3328,3478) pw_ws =====
__global__ __launch_bounds__(256) void k_prep(const float* __restrict__ doc,
                                              const float* __restrict__ attn_w,
                                              const float* __restrict__ attn_b,
                                              unsigned short* __restrict__ docb,
                                              float* __restrict__ ewa,
                                              int* __restrict__ hist,
                                              const float* __restrict__ mlp1_w,
                                              unsigned short* __restrict__ Bt,
                                              const float* __restrict__ width_emb,
                                              const float* __restrict__ mlp1_b,
                                              float* __restrict__ PW,
                                              const float* __restrict__ wp_emb,
                                              const float* __restrict__ w1,
                                              const float* __restrict__ b1,
                                              const float* __restrict__ w2,
                                              const float* __restrict__ b2,
                                              float* __restrict__ wscore) {
    __shared__ float sh[32][33];
    __shared__ float red[256];
    int bx = blockIdx.x;
    int tid = threadIdx.x;
    if (bx < 1024) {
        // ---- doc_prep ----
        if (bx < 16) hist[bx * 256 + tid] = 0;
        int row = bx * 4 + (tid >> 6);
        int lane = tid & 63;
        const float* r = doc + (size_t)row * H;
        float s = 0.f;
        #pragma unroll
        for (int q = 0; q < 3; ++q) {
            int idx = q * 256 + lane * 4;
            float4 v = *reinterpret_cast<const float4*>(r + idx);
            float4 w = *reinterpret_cast<const float4*>(attn_w + idx);
            s += v.x * w.x + v.y * w.y + v.z * w.z + v.w * w.w;
            ushort4 o;
            o.x = f2bf(v.x); o.y = f2bf(v.y); o.z = f2bf(v.z); o.w = f2bf(v.w);
            *reinterpret_cast<ushort4*>(docb + (size_t)row * H + idx) = o;
        }
        #pragma unroll
        for (int off = 32; off > 0; off >>= 1) s += __shfl_down(s, off);
        if (lane == 0) ewa[row] = expf(s + attn_b[0]);
    } else if (bx < 3328) {
        // ---- cvt_bt ----
        int idx = bx - 1024;                    // 0..2303
        int k0 = (idx % 24) * 32;
        int m0 = ((idx / 24) % 32) * 32;
        int part = idx / (24 * 32);
        int rb = part == 0 ? 0 : (part == 1 ? H : (2 * H + E));
        int tx = tid & 31, ty = tid >> 5;
        #pragma unroll
        for (int it = 0; it < 4; ++it) {
            int kk = ty + it * 8;
            sh[kk][tx] = mlp1_w[(size_t)(rb + k0 + kk) * M + m0 + tx];
        }
        __syncthreads();
        #pragma unroll
        for (int it = 0; it < 4; ++it) {
            int mm = ty + it * 8;
            Bt[(size_t)(part * M + m0 + mm) * H + k0 + tx] = f2bf(sh[tx][mm]);
        }
    } else {
        // ---- pw_ws ----
        int idx = bx - 3328;                    // 0..149
        int w = idx / 5, y = idx % 5;
        if (y < 4) {
            int m = y * 256 + tid;
            float acc = mlp1_b[m];
            #pragma unroll
            for (int e = 0; e < E; ++e)
                acc += width_emb[w * E + e] * mlp1_w[(size_t)(2 * H + e) * M + m];
            PW[w * M + m] = acc;
        } else {
            float part = 0.f;
            for (int m = tid; m < M; m += 256) {
                float h = b1[m];
                #pragma unroll
                for (int e = 0; e < E; ++e) h += wp_emb[w * E + e] * w1[e * M + m];
                part += fmaxf(h, 0.f) * w2[m];
            }
            red[tid] = part;
            __syncthreads();
            for (int s = 128; s > 0; s >>= 1) {
                if (tid < s) red[tid] += red[tid + s];
                __syncthreads();
            }
            if (tid == 0) wscore[w] = red[0] + b2[0];
        }
    }
}

// ------- merged scans: block0 = Dpre from ewa; block1 = offs+begs from hist -------
__global__ __launch_bounds__(256) void k_scans2(const float* __restrict__ ewa,
                                                float* __restrict__ Dpre,
                                                const int* __restrict__ hist,
                                                int* __restrict__ offs,
                                                int* __restrict__ begs) {
    __shared__ float shf[256];
    __shared__ int shi[256];
    int t = threadIdx.x;
    if (blockIdx.x == 0) {
        float v[16];
        float sum = 0.f;
        #pragma unroll
        for (int i = 0; i < 16; ++i) { v[i] = ewa[t * 16 + i]; sum += v[i]; }
        shf[t] = sum;
        __syncthreads();
        for (int off = 1; off < 256; off <<= 1) {
            float x = (t >= off) ? shf[t - off] : 0.f;
            __syncthreads();
            shf[t] += x;
            __syncthreads();
        }
        float run = shf[t] - sum;
        #pragma unroll
        for (int i = 0; i < 16; ++i) { run += v[i]; Dpre[t * 16 + i + 1] = run; }
        if (t == 0) Dpre[0] = 0.f;
    } else {
        int v[16];
        int sum = 0;
        #pragma unroll
        for (int i = 0; i < 16; ++i) { v[i] = hist[t * 16 + i]; sum += v[i]; }
        shi[t] = sum;
        __syncthreads();
        for (int off = 1; off < 256; off <<= 1) {
            int x = (t >= off) ? shi[t - off] : 0;
            __syncthreads();
            shi[t] += x;
            __syncthreads();
        }
        int run = shi[t] - sum;
        #pragma unroll
        for (int i = 0; i < 16; ++i) {
            offs[t * 16 + i] = run;
            begs[t * 16 + i] = run;
            run += v[i];
        }
        if (t == 255) begs[4096] = run;   // == NC
    }
}

// ---------------- sort-by-start: hist / scatter ----------------
__global__ __launch_bounds__(256) void k_hist(const int* __restrict__ starts,
                                              int* __restrict__ hist) {
    atomicAdd(&hist[starts[blockIdx.x * 256 + threadIdx.x]], 1);
}
__global__ __launch_bounds__(256) void k_scatter(const int* __restrict__ starts,
                                                 int* __restrict__ offs,
                                                 int* __restrict__ perm) {
    int c = blockIdx.x * 256 + threadIdx.x;
    int p = atomicAdd(&offs[starts[c]], 1);
    perm[p] = c;
}

// ---------------- MFMA projection (r9 config + NT C-writes) ----------
// 256x192 tile, 8 waves, fragment-ordered LDS, double-buffered, counted vmcnt(7).
// NEW: Pse/Sbuf stores are NON-TEMPORAL (nt flag) so the 33MB C-stream does not
// evict docb/Bt operand panels from the per-XCD L2 -> staging loads stay L2-hit
// and the vmcnt(7) drain hides under the MFMA cluster.
__global__ __launch_bounds__(512, 2) void k_proj_mfma(const unsigned short* __restrict__ docb,
                                                      const unsigned short* __restrict__ Bt,
                                                      const float* __restrict__ ewa,
                                                      unsigned short* __restrict__ Pse,
                                                      float* __restrict__ Sbuf,
                                                      float* __restrict__ T) {
    __shared__ unsigned short As[2][16384];  // [buf][mg:16][ks:2][g:4][ri:16][j:8] 64KB
    __shared__ unsigned short Bs[2][12288];  // [buf][cg:12][ks:2][g:4][ci:16][j:8] 48KB
    int tid = threadIdx.x;
    int bid = blockIdx.x;
    int xcd = bid & 7, rr0 = bid >> 3;
    int coltile = (xcd & 1) * 8 + (rr0 & 7);
    int rowtile = (xcd >> 1) * 4 + (rr0 >> 3);
    int col0 = coltile * 192;
    int row0 = rowtile * 256;
    int wv = tid >> 6, lane = tid & 63;
    int wr = wv >> 2, wc = wv & 3;

    f32x4 acc[8][3];
    #pragma unroll
    for (int mi = 0; mi < 8; ++mi)
        #pragma unroll
        for (int ni = 0; ni < 3; ++ni) acc[mi][ni] = (f32x4){0.f, 0.f, 0.f, 0.f};

    #define STAGE(buf, k0)                                                            \
        {                                                                             \
            _Pragma("unroll")                                                         \
            for (int i = 0; i < 4; ++i) {                                             \
                int s = i * 512 + tid;                                                \
                int mg = s >> 7, ks = (s >> 6) & 1, g = (s >> 4) & 3, ri = s & 15;    \
                gload16(docb + (size_t)(row0 + mg * 16 + ri) * H + (k0) + ks * 32 + g * 8, \
                        (char*)As[buf] + s * 16);                                     \
            }                                                                         \
            _Pragma("unroll")                                                         \
            for (int i = 0; i < 3; ++i) {                                             \
                int s = i * 512 + tid;                                                \
                int cg = s >> 7, ks = (s >> 6) & 1, g = (s >> 4) & 3, ci = s & 15;    \
                gload16(Bt + (size_t)(col0 + cg * 16 + ci) * H + (k0) + ks * 32 + g * 8, \
                        (char*)Bs[buf] + s * 16);                                     \
            }                                                                         \
        }

    STAGE(0, 0);
    STAGE(1, 64);
    asm volatile("s_waitcnt vmcnt(7)" ::: "memory");
    __builtin_amdgcn_s_barrier();

    #pragma unroll 1
    for (int t = 0; t < NKT; ++t) {
        int cur = t & 1;
        bf16x8 af[2][8], bfr[2][3];
        #pragma unroll
        for (int ks = 0; ks < 2; ++ks) {
            #pragma unroll
            for (int mi = 0; mi < 8; ++mi)
                af[ks][mi] = *reinterpret_cast<const bf16x8*>(
                    (char*)As[cur] + (wr * 8 + mi) * 2048 + ks * 1024 + lane * 16);
            #pragma unroll
            for (int ni = 0; ni < 3; ++ni)
                bfr[ks][ni] = *reinterpret_cast<const bf16x8*>(
                    (char*)Bs[cur] + (wc * 3 + ni) * 2048 + ks * 1024 + lane * 16);
        }
        __builtin_amdgcn_s_setprio(1);
        #pragma unroll
        for (int ks = 0; ks < 2; ++ks)
            #pragma unroll
            for (int mi = 0; mi < 8; ++mi)
                #pragma unroll
                for (int ni = 0; ni < 3; ++ni)
                    acc[mi][ni] = __builtin_amdgcn_mfma_f32_16x16x32_bf16(
                        af[ks][mi], bfr[ks][ni], acc[mi][ni], 0, 0, 0);
        __builtin_amdgcn_s_setprio(0);
        if (t + 2 < NKT) {
            asm volatile("s_waitcnt lgkmcnt(0)" ::: "memory");
            __builtin_amdgcn_sched_barrier(0);
            __builtin_amdgcn_s_barrier();
            STAGE(cur, (t + 2) * 64);
            asm volatile("s_waitcnt vmcnt(7)" ::: "memory");
            __builtin_amdgcn_s_barrier();
        } else if (t + 2 == NKT) {
            asm volatile("s_waitcnt vmcnt(0)" ::: "memory");
            __builtin_amdgcn_s_barrier();
        }
    }
    #undef STAGE

    int cr = (lane >> 4) * 4;
    int cc = lane & 15;
    #pragma unroll
    for (int mi = 0; mi < 8; ++mi) {
        #pragma unroll
        for (int ni = 0; ni < 3; ++ni) {
            int rrow = row0 + wr * 128 + mi * 16 + cr;
            int cabs = col0 + wc * 48 + ni * 16 + cc;
            int part = cabs >> 10;
            int cm = cabs & 1023;
            if (part < 2) {
                unsigned short* dst = Pse + (size_t)rrow * 2048 + part * 1024 + cm;
                #pragma unroll
                for (int j = 0; j < 4; ++j)
                    __builtin_nontemporal_store(f2bf(acc[mi][ni][j]), dst + (size_t)j * 2048);
            } else {
                float* dst = Sbuf + (size_t)rrow * M + cm;
                #pragma unroll
                for (int j = 0; j < 4; ++j)
                    __builtin_nontemporal_store(acc[mi][ni][j], dst + (size_t)j * M);
            }
        }
    }
    // ---- chunk totals T (scan1 fused): mi-halves of the wave's 128 rows = 2 chunks ----
    #pragma unroll
    for (int half = 0; half < 2; ++half) {
        int chunk = (row0 >> 6) + wr * 2 + half;
        #pragma unroll
        for (int ni = 0; ni < 3; ++ni) {
            int cabs = col0 + wc * 48 + ni * 16 + cc;
            if (cabs >= 2048) {
                float psum = 0.f;
                #pragma unroll
                for (int mi4 = 0; mi4 < 4; ++mi4) {
                    int mi = half * 4 + mi4;
                    int rbase = row0 + wr * 128 + mi * 16 + cr;
                    #pragma unroll
                    for (int j = 0; j < 4; ++j)
                        psum += ewa[rbase + j] * acc[mi][ni][j];
                }
                psum += __shfl_down(psum, 16);
                psum += __shfl_down(psum, 32);
                if ((lane >> 4) == 0)
                    T[(size_t)chunk * M + (cabs - 2048)] = psum;
            }
        }
    }
}

// ---------------- scan phase 2: exclusive scan of chunk totals (reg-resident) ----------------
__global__ __launch_bounds__(256) void k_scan2(float* __restrict__ T) {
    int m = blockIdx.x * 256 + threadIdx.x;
    float v[NCH];
    #pragma unroll
    for (int c = 0; c < NCH; ++c) v[c] = T[c * M + m];
    float run = 0.f;
    #pragma unroll
    for (int c = 0; c < NCH; ++c) { float t = v[c]; T[c * M + m] = run; run += t; }
}

// ---------------- scan phase 3: in-place inclusive prefix over Sbuf ----------------
__global__ __launch_bounds__(256) void k_scan3(float* __restrict__ Sbuf,
                                               const float* __restrict__ ewa,
                                               const float* __restrict__ T) {
    int m = blockIdx.x * 256 + threadIdx.x;
    int c = blockIdx.y;
    __shared__ float ew[CHUNK];
    if (threadIdx.x < CHUNK) ew[threadIdx.x] = ewa[c * CHUNK + threadIdx.x];
    __syncthreads();
    float acc = T[c * M + m];
    float* base = Sbuf + (size_t)(c * CHUNK) * M + m;
    #pragma unroll 4
    for (int i = 0; i < CHUNK; ++i) {
        float* p = base + (size_t)i * M;
        acc += ew[i] * (*p);
        *p = acc;
    }
}

// ---------------- per-START candidate scoring: one block per start value ----------------
__global__ __launch_bounds__(256) void k_cand(const unsigned short* __restrict__ Pse,
                                              const float* __restrict__ Sbuf,
                                              const float* __restrict__ PW,
                                              const float* __restrict__ Dpre,
                                              const float* __restrict__ wscore,
                                              const int* __restrict__ perm,
                                              const int* __restrict__ begs,
                                              const int* __restrict__ ends,
                                              const float* __restrict__ mlp2_w,
                                              const float* __restrict__ mlp2_b,
                                              float* __restrict__ out) {
    __shared__ __align__(16) unsigned short ps_l[1024];
    __shared__ __align__(16) float ss_l[1024];
    int bid = blockIdx.x;                           // 4096 blocks, %8==0 -> bijective
    int s = (bid & 7) * 512 + (bid >> 3);           // XCD-contiguous start ranges
    int tid = threadIdx.x;
    {
        ushort4 p4 = *reinterpret_cast<const ushort4*>(Pse + (size_t)s * 2048 + tid * 4);
        *reinterpret_cast<ushort4*>(ps_l + tid * 4) = p4;
        float4 s4 = (s > 0) ? *reinterpret_cast<const float4*>(Sbuf + (size_t)(s - 1) * M + tid * 4)
                            : make_float4(0.f, 0.f, 0.f, 0.f);
        *reinterpret_cast<float4*>(ss_l + tid * 4) = s4;
    }
    __syncthreads();
    int beg = begs[s], end = begs[s + 1];
    int wv = tid >> 6, lane = tid & 63;
    float dps = Dpre[s];
    // hoist candidate-invariant mlp2_w into registers
    float4 v00 = *reinterpret_cast<const float4*>(mlp2_w + lane * 8);
    float4 v01 = *reinterpret_cast<const float4*>(mlp2_w + lane * 8 + 4);
    float4 v10 = *reinterpret_cast<const float4*>(mlp2_w + lane * 8 + 512);
    float4 v11 = *reinterpret_cast<const float4*>(mlp2_w + lane * 8 + 516);

    for (int j = beg + wv; j < end; j += 4) {
        int c = perm[j];
        int e = ends[c];
        int wi = e - s;
        wi = wi > MSW - 1 ? MSW - 1 : wi;
        float inv = 1.f / (Dpre[e + 1] - dps);
        const unsigned short* pe = Pse + (size_t)e * 2048 + 1024;
        const float* se = Sbuf + (size_t)e * M;
        const float* pw = PW + (size_t)wi * M;

        float part = 0.f;
        #pragma unroll
        for (int q = 0; q < 2; ++q) {
            int m = lane * 8 + q * 512;
            u16x8 a8 = *reinterpret_cast<const u16x8*>(ps_l + m);
            u16x8 b8 = *reinterpret_cast<const u16x8*>(pe + m);
            float4 t0 = *reinterpret_cast<const float4*>(se + m);
            float4 t1 = *reinterpret_cast<const float4*>(se + m + 4);
            float4 u0 = *reinterpret_cast<const float4*>(ss_l + m);
            float4 u1 = *reinterpret_cast<const float4*>(ss_l + m + 4);
            float4 w0 = *reinterpret_cast<const float4*>(pw + m);
            float4 w1 = *reinterpret_cast<const float4*>(pw + m + 4);
            float4 v0 = q ? v10 : v00;
            float4 v1 = q ? v11 : v01;
            float x;
            x = bf2f(a8[0]) + bf2f(b8[0]) + w0.x + (t0.x - u0.x) * inv; part += fmaxf(x, 0.f) * v0.x;
            x = bf2f(a8[1]) + bf2f(b8[1]) + w0.y + (t0.y - u0.y) * inv; part += fmaxf(x, 0.f) * v0.y;
            x = bf2f(a8[2]) + bf2f(b8[2]) + w0.z + (t0.z - u0.z) * inv; part += fmaxf(x, 0.f) * v0.z;
            x = bf2f(a8[3]) + bf2f(b8[3]) + w0.w + (t0.w - u0.w) * inv; part += fmaxf(x, 0.f) * v0.w;
            x = bf2f(a8[4]) + bf2f(b8[4]) + w1.x + (t1.x - u1.x) * inv; part += fmaxf(x, 0.f) * v1.x;
            x = bf2f(a8[5]) + bf2f(b8[5]) + w1.y + (t1.y - u1.y) * inv; part += fmaxf(x, 0.f) * v1.y;
            x = bf2f(a8[6]) + bf2f(b8[6]) + w1.z + (t1.z - u1.z) * inv; part += fmaxf(x, 0.f) * v1.z;
            x = bf2f(a8[7]) + bf2f(b8[7]) + w1.w + (t1.w - u1.w) * inv; part += fmaxf(x, 0.f) * v1.w;
        }
        #pragma unroll
        for (int off = 32; off > 0; off >>= 1) part += __shfl_down(part, off);
        if (lane == 0) out[c] = part + mlp2_b[0] + wscore[wi];
    }
}

extern "C" void kernel_launch(void* const* d_in, const int* in_sizes, int n_in,
                              void* d_out, int out_size, void* d_ws, size_t ws_size,
                              hipStream_t stream) {
    const float* encoded_doc = (const float*)d_in[0];
    const int*   cand_starts = (const int*)d_in[1];
    const int*   cand_ends   = (const int*)d_in[2];
    const float* width_emb   = (const float*)d_in[3];
    const float* width_prior = (const float*)d_in[4];
    const float* attn_w      = (const float*)d_in[5];
    const float* attn_b      = (const float*)d_in[6];
    const float* mlp1_w      = (const float*)d_in[7];
    const float* mlp1_b      = (const float*)d_in[8];
    const float* mlp2_w      = (const float*)d_in[9];
    const float* mlp2_b      = (const float*)d_in[10];
    const float* wmlp1_w     = (const float*)d_in[11];
    const float* wmlp1_b     = (const float*)d_in[12];
    const float* wmlp2_w     = (const float*)d_in[13];
    const float* wmlp2_b     = (const float*)d_in[14];
    float* out = (float*)d_out;

    // workspace layout (float units from base; all large blocks 16B-aligned)
    float* Sbuf   = (float*)d_ws;                      // NW*1024
    float* T      = Sbuf + (size_t)NW * M;             // NCH*M = 65536
    float* PW     = T + NCH * M;                       // 30*1024
    float* ewa    = PW + MSW * M;                      // 4096
    float* Dpre   = ewa + NW;                          // 4160
    float* wscore = Dpre + 4160;                       // 64
    unsigned short* Pse  = (unsigned short*)(wscore + 64);      // NW*2048 bf16
    unsigned short* docb = Pse + (size_t)NW * 2048;             // NW*H bf16
    unsigned short* Btb  = docb + (size_t)NW * H;               // 3072*H bf16
    int* hist = (int*)(Btb + (size_t)3072 * H);        // 4096
    int* offs = hist + 4096;                           // 4096
    int* begs = offs + 4096;                           // 4097 (pad 4112)
    int* perm = begs + 4112;                           // NC

    k_prep<<<3478, 256, 0, stream>>>(encoded_doc, attn_w, attn_b, docb, ewa, hist,
                                     mlp1_w, Btb, width_emb, mlp1_b, PW,
                                     width_prior, wmlp1_w, wmlp1_b, wmlp2_w, wmlp2_b, wscore);
    k_hist<<<NC / 256, 256, 0, stream>>>(cand_starts, hist);
    k_scans2<<<2, 256, 0, stream>>>(ewa, Dpre, hist, offs, begs);
    k_scatter<<<NC / 256, 256, 0, stream>>>(cand_starts, offs, perm);
    k_proj_mfma<<<256, 512, 0, stream>>>(docb, Btb, ewa, Pse, Sbuf, T);
    k_scan2<<<M / 256, 256, 0, stream>>>(T);
    k_scan3<<<dim3(M / 256, NCH), 256, 0, stream>>>(Sbuf, ewa, T);
    k_cand<<<4096, 256, 0, stream>>>(Pse, Sbuf, PW, Dpre, wscore, perm, begs,
                                     cand_ends, mlp2_w, mlp2_b, out);
}

// Round 14
// 118.391 us; speedup vs baseline: 1.0746x; 1.0746x over previous
//
#include <hip/hip_runtime.h>
#include <math.h>

#define NW 4096
#define H 768
#define NC 49152
#define MSW 30
#define E 20
#define M 1024
#define CHUNK 64
#define NCH (NW / CHUNK)
#define NKT2 (H / 128)   // 6 K-tiles of 128
// Pse: bf16 [NW][2048] (cols 0:1024 start-proj, 1024:2048 end-proj)
// Sbuf: f32 [NW][1024] attn-proj, overwritten in place by exp-weighted prefix:
//   Sbuf[r][m] = S[r+1][m] = sum_{i<=r} ewa[i]*Pattn[i][m]

typedef short bf16x8 __attribute__((ext_vector_type(8)));
typedef unsigned short u16x8 __attribute__((ext_vector_type(8)));
typedef float f32x4 __attribute__((ext_vector_type(4)));

__device__ __forceinline__ unsigned short f2bf(float x) {
    unsigned u = __float_as_uint(x);
    return (unsigned short)((u + 0x7fff + ((u >> 16) & 1)) >> 16);  // RNE
}
__device__ __forceinline__ float bf2f(unsigned short b) {
    return __uint_as_float(((unsigned)b) << 16);
}
__device__ __forceinline__ void gload16(const void* g, void* l) {
    __builtin_amdgcn_global_load_lds((const __attribute__((address_space(1))) void*)g,
                                     (__attribute__((address_space(3))) void*)l, 16, 0, 0);
}

// ===== merged preprocessing: [0,1024) doc_prep+hist-zero | [1024,3328) cvt_bt | [3328,3478) pw_ws =====
__global__ __launch_bounds__(256) void k_prep(const float* __restrict__ doc,
                                              const float* __restrict__ attn_w,
                                              const float* __restrict__ attn_b,
                                              unsigned short* __restrict__ docb,
                                              float* __restrict__ ewa,
                                              int* __restrict__ hist,
                                              const float* __restrict__ mlp1_w,
                                              unsigned short* __restrict__ Bt,
                                              const float* __restrict__ width_emb,
                                              const float* __restrict__ mlp1_b,
                                              float* __restrict__ PW,
                                              const float* __restrict__ wp_emb,
                                              const float* __restrict__ w1,
                                              const float* __restrict__ b1,
                                              const float* __restrict__ w2,
                                              const float* __restrict__ b2,
                                              float* __restrict__ wscore) {
    __shared__ float sh[32][33];
    __shared__ float red[256];
    int bx = blockIdx.x;
    int tid = threadIdx.x;
    if (bx < 1024) {
        // ---- doc_prep ----
        if (bx < 16) hist[bx * 256 + tid] = 0;
        int row = bx * 4 + (tid >> 6);
        int lane = tid & 63;
        const float* r = doc + (size_t)row * H;
        float s = 0.f;
        #pragma unroll
        for (int q = 0; q < 3; ++q) {
            int idx = q * 256 + lane * 4;
            float4 v = *reinterpret_cast<const float4*>(r + idx);
            float4 w = *reinterpret_cast<const float4*>(attn_w + idx);
            s += v.x * w.x + v.y * w.y + v.z * w.z + v.w * w.w;
            ushort4 o;
            o.x = f2bf(v.x); o.y = f2bf(v.y); o.z = f2bf(v.z); o.w = f2bf(v.w);
            *reinterpret_cast<ushort4*>(docb + (size_t)row * H + idx) = o;
        }
        #pragma unroll
        for (int off = 32; off > 0; off >>= 1) s += __shfl_down(s, off);
        if (lane == 0) ewa[row] = expf(s + attn_b[0]);
    } else if (bx < 3328) {
        // ---- cvt_bt ----
        int idx = bx - 1024;                    // 0..2303
        int k0 = (idx % 24) * 32;
        int m0 = ((idx / 24) % 32) * 32;
        int part = idx / (24 * 32);
        int rb = part == 0 ? 0 : (part == 1 ? H : (2 * H + E));
        int tx = tid & 31, ty = tid >> 5;
        #pragma unroll
        for (int it = 0; it < 4; ++it) {
            int kk = ty + it * 8;
            sh[kk][tx] = mlp1_w[(size_t)(rb + k0 + kk) * M + m0 + tx];
        }
        __syncthreads();
        #pragma unroll
        for (int it = 0; it < 4; ++it) {
            int mm = ty + it * 8;
            Bt[(size_t)(part * M + m0 + mm) * H + k0 + tx] = f2bf(sh[tx][mm]);
        }
    } else {
        // ---- pw_ws ----
        int idx = bx - 3328;                    // 0..149
        int w = idx / 5, y = idx % 5;
        if (y < 4) {
            int m = y * 256 + tid;
            float acc = mlp1_b[m];
            #pragma unroll
            for (int e = 0; e < E; ++e)
                acc += width_emb[w * E + e] * mlp1_w[(size_t)(2 * H + e) * M + m];
            PW[w * M + m] = acc;
        } else {
            float part = 0.f;
            for (int m = tid; m < M; m += 256) {
                float h = b1[m];
                #pragma unroll
                for (int e = 0; e < E; ++e) h += wp_emb[w * E + e] * w1[e * M + m];
                part += fmaxf(h, 0.f) * w2[m];
            }
            red[tid] = part;
            __syncthreads();
            for (int s = 128; s > 0; s >>= 1) {
                if (tid < s) red[tid] += red[tid + s];
                __syncthreads();
            }
            if (tid == 0) wscore[w] = red[0] + b2[0];
        }
    }
}

// ------- merged scans: block0 = Dpre from ewa; block1 = offs+begs from hist -------
__global__ __launch_bounds__(256) void k_scans2(const float* __restrict__ ewa,
                                                float* __restrict__ Dpre,
                                                const int* __restrict__ hist,
                                                int* __restrict__ offs,
                                                int* __restrict__ begs) {
    __shared__ float shf[256];
    __shared__ int shi[256];
    int t = threadIdx.x;
    if (blockIdx.x == 0) {
        float v[16];
        float sum = 0.f;
        #pragma unroll
        for (int i = 0; i < 16; ++i) { v[i] = ewa[t * 16 + i]; sum += v[i]; }
        shf[t] = sum;
        __syncthreads();
        for (int off = 1; off < 256; off <<= 1) {
            float x = (t >= off) ? shf[t - off] : 0.f;
            __syncthreads();
            shf[t] += x;
            __syncthreads();
        }
        float run = shf[t] - sum;
        #pragma unroll
        for (int i = 0; i < 16; ++i) { run += v[i]; Dpre[t * 16 + i + 1] = run; }
        if (t == 0) Dpre[0] = 0.f;
    } else {
        int v[16];
        int sum = 0;
        #pragma unroll
        for (int i = 0; i < 16; ++i) { v[i] = hist[t * 16 + i]; sum += v[i]; }
        shi[t] = sum;
        __syncthreads();
        for (int off = 1; off < 256; off <<= 1) {
            int x = (t >= off) ? shi[t - off] : 0;
            __syncthreads();
            shi[t] += x;
            __syncthreads();
        }
        int run = shi[t] - sum;
        #pragma unroll
        for (int i = 0; i < 16; ++i) {
            offs[t * 16 + i] = run;
            begs[t * 16 + i] = run;
            run += v[i];
        }
        if (t == 255) begs[4096] = run;   // == NC
    }
}

// ---------------- sort-by-start: hist / scatter ----------------
__global__ __launch_bounds__(256) void k_hist(const int* __restrict__ starts,
                                              int* __restrict__ hist) {
    atomicAdd(&hist[starts[blockIdx.x * 256 + threadIdx.x]], 1);
}
__global__ __launch_bounds__(256) void k_scatter(const int* __restrict__ starts,
                                                 int* __restrict__ offs,
                                                 int* __restrict__ perm) {
    int c = blockIdx.x * 256 + threadIdx.x;
    int p = atomicAdd(&offs[starts[c]], 1);
    perm[p] = c;
}

// ---------------- MFMA projection: BM=128 BN=192 BK=128, 160KB LDS, 6 K-steps --------
// Halves the barrier-pair/drain count vs BK=64 (6 vs 12) while keeping per-step FLOP;
// each step has 2x MFMA work under which the staging-load latency hides.
// Fragment-ordered LDS [mg/cg][ks:4][g:4][ri:16][j:8] (linear ds_reads, 0 conflicts),
// double-buffered, counted vmcnt(10). Epilogue emits chunk totals T (scan1 fused).
__global__ __launch_bounds__(512, 1) void k_proj_mfma(const unsigned short* __restrict__ docb,
                                                      const unsigned short* __restrict__ Bt,
                                                      const float* __restrict__ ewa,
                                                      unsigned short* __restrict__ Pse,
                                                      float* __restrict__ Sbuf,
                                                      float* __restrict__ T) {
    __shared__ unsigned short As[2][16384];  // [buf][mg:8][ks:4][g:4][ri:16][j:8]  64KB
    __shared__ unsigned short Bs[2][24576];  // [buf][cg:12][ks:4][g:4][ci:16][j:8] 96KB
    int tid = threadIdx.x;
    int bid = blockIdx.x;                            // 512 blocks
    int xcd = bid & 7, rr0 = bid >> 3;               // rr0: 0..63
    int coltile = (xcd & 1) * 8 + (rr0 & 7);         // 0..15
    int rowtile = (xcd >> 1) * 8 + (rr0 >> 3);       // 0..31
    int col0 = coltile * 192;
    int row0 = rowtile * 128;
    int wv = tid >> 6, lane = tid & 63;
    int wr = wv >> 2, wc = wv & 3;                   // 2M x 4N waves; wave tile 64x48

    f32x4 acc[4][3];
    #pragma unroll
    for (int mi = 0; mi < 4; ++mi)
        #pragma unroll
        for (int ni = 0; ni < 3; ++ni) acc[mi][ni] = (f32x4){0.f, 0.f, 0.f, 0.f};

    // 10 gload16 per thread per K-tile (4 A + 6 B) -> vmcnt(10) == prev tile landed
    #define STAGE(buf, k0)                                                            \
        {                                                                             \
            _Pragma("unroll")                                                         \
            for (int i = 0; i < 4; ++i) {                                             \
                int s = i * 512 + tid;                                                \
                int mg = s >> 8, ks = (s >> 6) & 3, g = (s >> 4) & 3, ri = s & 15;    \
                gload16(docb + (size_t)(row0 + mg * 16 + ri) * H + (k0) + ks * 32 + g * 8, \
                        (char*)As[buf] + s * 16);                                     \
            }                                                                         \
            _Pragma("unroll")                                                         \
            for (int i = 0; i < 6; ++i) {                                             \
                int s = i * 512 + tid;                                                \
                int cg = s >> 8, ks = (s >> 6) & 3, g = (s >> 4) & 3, ci = s & 15;    \
                gload16(Bt + (size_t)(col0 + cg * 16 + ci) * H + (k0) + ks * 32 + g * 8, \
                        (char*)Bs[buf] + s * 16);                                     \
            }                                                                         \
        }

    STAGE(0, 0);
    STAGE(1, 128);
    asm volatile("s_waitcnt vmcnt(10)" ::: "memory");  // tile 0 landed (tile 1 in flight)
    __builtin_amdgcn_s_barrier();

    #pragma unroll 1
    for (int t = 0; t < NKT2; ++t) {
        int cur = t & 1;
        #pragma unroll
        for (int ks = 0; ks < 4; ++ks) {
            bf16x8 af[4], bfr[3];
            #pragma unroll
            for (int mi = 0; mi < 4; ++mi)
                af[mi] = *reinterpret_cast<const bf16x8*>(
                    (char*)As[cur] + (wr * 4 + mi) * 4096 + ks * 1024 + lane * 16);
            #pragma unroll
            for (int ni = 0; ni < 3; ++ni)
                bfr[ni] = *reinterpret_cast<const bf16x8*>(
                    (char*)Bs[cur] + (wc * 3 + ni) * 4096 + ks * 1024 + lane * 16);
            __builtin_amdgcn_s_setprio(1);
            #pragma unroll
            for (int mi = 0; mi < 4; ++mi)
                #pragma unroll
                for (int ni = 0; ni < 3; ++ni)
                    acc[mi][ni] = __builtin_amdgcn_mfma_f32_16x16x32_bf16(
                        af[mi], bfr[ni], acc[mi][ni], 0, 0, 0);
            __builtin_amdgcn_s_setprio(0);
        }
        if (t + 2 < NKT2) {
            asm volatile("s_waitcnt lgkmcnt(0)" ::: "memory");  // all buf[cur] reads retired
            __builtin_amdgcn_sched_barrier(0);
            __builtin_amdgcn_s_barrier();                       // block-wide: buf[cur] free
            STAGE(cur, (t + 2) * 128);                          // overwrite buf[cur] w/ t+2
            asm volatile("s_waitcnt vmcnt(10)" ::: "memory");   // tile t+1 landed
            __builtin_amdgcn_s_barrier();                       // buf[cur^1] ready
        } else if (t + 2 == NKT2) {
            asm volatile("s_waitcnt vmcnt(0)" ::: "memory");    // drain last tile
            __builtin_amdgcn_s_barrier();
        }
    }
    #undef STAGE

    int cr = (lane >> 4) * 4;
    int cc = lane & 15;
    #pragma unroll
    for (int mi = 0; mi < 4; ++mi) {
        #pragma unroll
        for (int ni = 0; ni < 3; ++ni) {
            int rrow = row0 + wr * 64 + mi * 16 + cr;
            int cabs = col0 + wc * 48 + ni * 16 + cc;
            int part = cabs >> 10;
            int cm = cabs & 1023;
            if (part < 2) {
                unsigned short* dst = Pse + (size_t)rrow * 2048 + part * 1024 + cm;
                #pragma unroll
                for (int j = 0; j < 4; ++j) dst[(size_t)j * 2048] = f2bf(acc[mi][ni][j]);
            } else {
                float* dst = Sbuf + (size_t)rrow * M + cm;
                #pragma unroll
                for (int j = 0; j < 4; ++j) dst[(size_t)j * M] = acc[mi][ni][j];
            }
        }
    }
    // ---- chunk totals T (scan1 fused): each wave's 64 rows = exactly one chunk ----
    {
        int chunk = (row0 >> 6) + wr;
        #pragma unroll
        for (int ni = 0; ni < 3; ++ni) {
            int cabs = col0 + wc * 48 + ni * 16 + cc;
            if (cabs >= 2048) {
                float psum = 0.f;
                #pragma unroll
                for (int mi = 0; mi < 4; ++mi) {
                    int rbase = row0 + wr * 64 + mi * 16 + cr;
                    #pragma unroll
                    for (int j = 0; j < 4; ++j)
                        psum += ewa[rbase + j] * acc[mi][ni][j];
                }
                psum += __shfl_down(psum, 16);
                psum += __shfl_down(psum, 32);
                if ((lane >> 4) == 0)
                    T[(size_t)chunk * M + (cabs - 2048)] = psum;
            }
        }
    }
}

// ---------------- scan phase 2: exclusive scan of chunk totals (reg-resident) ----------------
__global__ __launch_bounds__(256) void k_scan2(float* __restrict__ T) {
    int m = blockIdx.x * 256 + threadIdx.x;
    float v[NCH];
    #pragma unroll
    for (int c = 0; c < NCH; ++c) v[c] = T[c * M + m];
    float run = 0.f;
    #pragma unroll
    for (int c = 0; c < NCH; ++c) { float t = v[c]; T[c * M + m] = run; run += t; }
}

// ---------------- scan phase 3: in-place inclusive prefix over Sbuf ----------------
__global__ __launch_bounds__(256) void k_scan3(float* __restrict__ Sbuf,
                                               const float* __restrict__ ewa,
                                               const float* __restrict__ T) {
    int m = blockIdx.x * 256 + threadIdx.x;
    int c = blockIdx.y;
    __shared__ float ew[CHUNK];
    if (threadIdx.x < CHUNK) ew[threadIdx.x] = ewa[c * CHUNK + threadIdx.x];
    __syncthreads();
    float acc = T[c * M + m];
    float* base = Sbuf + (size_t)(c * CHUNK) * M + m;
    #pragma unroll 4
    for (int i = 0; i < CHUNK; ++i) {
        float* p = base + (size_t)i * M;
        acc += ew[i] * (*p);
        *p = acc;
    }
}

// ---------------- per-START candidate scoring: one block per start value ----------------
__global__ __launch_bounds__(256) void k_cand(const unsigned short* __restrict__ Pse,
                                              const float* __restrict__ Sbuf,
                                              const float* __restrict__ PW,
                                              const float* __restrict__ Dpre,
                                              const float* __restrict__ wscore,
                                              const int* __restrict__ perm,
                                              const int* __restrict__ begs,
                                              const int* __restrict__ ends,
                                              const float* __restrict__ mlp2_w,
                                              const float* __restrict__ mlp2_b,
                                              float* __restrict__ out) {
    __shared__ __align__(16) unsigned short ps_l[1024];
    __shared__ __align__(16) float ss_l[1024];
    int bid = blockIdx.x;                           // 4096 blocks, %8==0 -> bijective
    int s = (bid & 7) * 512 + (bid >> 3);           // XCD-contiguous start ranges
    int tid = threadIdx.x;
    {
        ushort4 p4 = *reinterpret_cast<const ushort4*>(Pse + (size_t)s * 2048 + tid * 4);
        *reinterpret_cast<ushort4*>(ps_l + tid * 4) = p4;
        float4 s4 = (s > 0) ? *reinterpret_cast<const float4*>(Sbuf + (size_t)(s - 1) * M + tid * 4)
                            : make_float4(0.f, 0.f, 0.f, 0.f);
        *reinterpret_cast<float4*>(ss_l + tid * 4) = s4;
    }
    __syncthreads();
    int beg = begs[s], end = begs[s + 1];
    int wv = tid >> 6, lane = tid & 63;
    float dps = Dpre[s];
    // hoist candidate-invariant mlp2_w into registers
    float4 v00 = *reinterpret_cast<const float4*>(mlp2_w + lane * 8);
    float4 v01 = *reinterpret_cast<const float4*>(mlp2_w + lane * 8 + 4);
    float4 v10 = *reinterpret_cast<const float4*>(mlp2_w + lane * 8 + 512);
    float4 v11 = *reinterpret_cast<const float4*>(mlp2_w + lane * 8 + 516);

    for (int j = beg + wv; j < end; j += 4) {
        int c = perm[j];
        int e = ends[c];
        int wi = e - s;
        wi = wi > MSW - 1 ? MSW - 1 : wi;
        float inv = 1.f / (Dpre[e + 1] - dps);
        const unsigned short* pe = Pse + (size_t)e * 2048 + 1024;
        const float* se = Sbuf + (size_t)e * M;
        const float* pw = PW + (size_t)wi * M;

        float part = 0.f;
        #pragma unroll
        for (int q = 0; q < 2; ++q) {
            int m = lane * 8 + q * 512;
            u16x8 a8 = *reinterpret_cast<const u16x8*>(ps_l + m);
            u16x8 b8 = *reinterpret_cast<const u16x8*>(pe + m);
            float4 t0 = *reinterpret_cast<const float4*>(se + m);
            float4 t1 = *reinterpret_cast<const float4*>(se + m + 4);
            float4 u0 = *reinterpret_cast<const float4*>(ss_l + m);
            float4 u1 = *reinterpret_cast<const float4*>(ss_l + m + 4);
            float4 w0 = *reinterpret_cast<const float4*>(pw + m);
            float4 w1 = *reinterpret_cast<const float4*>(pw + m + 4);
            float4 v0 = q ? v10 : v00;
            float4 v1 = q ? v11 : v01;
            float x;
            x = bf2f(a8[0]) + bf2f(b8[0]) + w0.x + (t0.x - u0.x) * inv; part += fmaxf(x, 0.f) * v0.x;
            x = bf2f(a8[1]) + bf2f(b8[1]) + w0.y + (t0.y - u0.y) * inv; part += fmaxf(x, 0.f) * v0.y;
            x = bf2f(a8[2]) + bf2f(b8[2]) + w0.z + (t0.z - u0.z) * inv; part += fmaxf(x, 0.f) * v0.z;
            x = bf2f(a8[3]) + bf2f(b8[3]) + w0.w + (t0.w - u0.w) * inv; part += fmaxf(x, 0.f) * v0.w;
            x = bf2f(a8[4]) + bf2f(b8[4]) + w1.x + (t1.x - u1.x) * inv; part += fmaxf(x, 0.f) * v1.x;
            x = bf2f(a8[5]) + bf2f(b8[5]) + w1.y + (t1.y - u1.y) * inv; part += fmaxf(x, 0.f) * v1.y;
            x = bf2f(a8[6]) + bf2f(b8[6]) + w1.z + (t1.z - u1.z) * inv; part += fmaxf(x, 0.f) * v1.z;
            x = bf2f(a8[7]) + bf2f(b8[7]) + w1.w + (t1.w - u1.w) * inv; part += fmaxf(x, 0.f) * v1.w;
        }
        #pragma unroll
        for (int off = 32; off > 0; off >>= 1) part += __shfl_down(part, off);
        if (lane == 0) out[c] = part + mlp2_b[0] + wscore[wi];
    }
}

extern "C" void kernel_launch(void* const* d_in, const int* in_sizes, int n_in,
                              void* d_out, int out_size, void* d_ws, size_t ws_size,
                              hipStream_t stream) {
    const float* encoded_doc = (const float*)d_in[0];
    const int*   cand_starts = (const int*)d_in[1];
    const int*   cand_ends   = (const int*)d_in[2];
    const float* width_emb   = (const float*)d_in[3];
    const float* width_prior = (const float*)d_in[4];
    const float* attn_w      = (const float*)d_in[5];
    const float* attn_b      = (const float*)d_in[6];
    const float* mlp1_w      = (const float*)d_in[7];
    const float* mlp1_b      = (const float*)d_in[8];
    const float* mlp2_w      = (const float*)d_in[9];
    const float* mlp2_b      = (const float*)d_in[10];
    const float* wmlp1_w     = (const float*)d_in[11];
    const float* wmlp1_b     = (const float*)d_in[12];
    const float* wmlp2_w     = (const float*)d_in[13];
    const float* wmlp2_b     = (const float*)d_in[14];
    float* out = (float*)d_out;

    // workspace layout (float units from base; all large blocks 16B-aligned)
    float* Sbuf   = (float*)d_ws;                      // NW*1024
    float* T      = Sbuf + (size_t)NW * M;             // NCH*M = 65536
    float* PW     = T + NCH * M;                       // 30*1024
    float* ewa    = PW + MSW * M;                      // 4096
    float* Dpre   = ewa + NW;                          // 4160
    float* wscore = Dpre + 4160;                       // 64
    unsigned short* Pse  = (unsigned short*)(wscore + 64);      // NW*2048 bf16
    unsigned short* docb = Pse + (size_t)NW * 2048;             // NW*H bf16
    unsigned short* Btb  = docb + (size_t)NW * H;               // 3072*H bf16
    int* hist = (int*)(Btb + (size_t)3072 * H);        // 4096
    int* offs = hist + 4096;                           // 4096
    int* begs = offs + 4096;                           // 4097 (pad 4112)
    int* perm = begs + 4112;                           // NC

    k_prep<<<3478, 256, 0, stream>>>(encoded_doc, attn_w, attn_b, docb, ewa, hist,
                                     mlp1_w, Btb, width_emb, mlp1_b, PW,
                                     width_prior, wmlp1_w, wmlp1_b, wmlp2_w, wmlp2_b, wscore);
    k_hist<<<NC / 256, 256, 0, stream>>>(cand_starts, hist);
    k_scans2<<<2, 256, 0, stream>>>(ewa, Dpre, hist, offs, begs);
    k_scatter<<<NC / 256, 256, 0, stream>>>(cand_starts, offs, perm);
    k_proj_mfma<<<512, 512, 0, stream>>>(docb, Btb, ewa, Pse, Sbuf, T);
    k_scan2<<<M / 256, 256, 0, stream>>>(T);
    k_scan3<<<dim3(M / 256, NCH), 256, 0, stream>>>(Sbuf, ewa, T);
    k_cand<<<4096, 256, 0, stream>>>(Pse, Sbuf, PW, Dpre, wscore, perm, begs,
                                     cand_ends, mlp2_w, mlp2_b, out);
}

// Round 15
// 111.345 us; speedup vs baseline: 1.1427x; 1.0633x over previous
//
#include <hip/hip_runtime.h>
#include <math.h>

#define NW 4096
#define H 768
#define NC 49152
#define MSW 30
#define E 20
#define M 1024
#define CHUNK 64
#define NCH (NW / CHUNK)
#define NKT (H / 64)   // 12 K-tiles of 64
// Pse: bf16 [NW][2048] (cols 0:1024 start-proj, 1024:2048 end-proj)
// Sbuf: f32 [NW][1024] attn-proj, overwritten in place by exp-weighted prefix:
//   Sbuf[r][m] = S[r+1][m] = sum_{i<=r} ewa[i]*Pattn[i][m]

typedef short bf16x8 __attribute__((ext_vector_type(8)));
typedef unsigned short u16x8 __attribute__((ext_vector_type(8)));
typedef float f32x16 __attribute__((ext_vector_type(16)));

__device__ __forceinline__ unsigned short f2bf(float x) {
    unsigned u = __float_as_uint(x);
    return (unsigned short)((u + 0x7fff + ((u >> 16) & 1)) >> 16);  // RNE
}
__device__ __forceinline__ float bf2f(unsigned short b) {
    return __uint_as_float(((unsigned)b) << 16);
}
__device__ __forceinline__ void gload16(const void* g, void* l) {
    __builtin_amdgcn_global_load_lds((const __attribute__((address_space(1))) void*)g,
                                     (__attribute__((address_space(3))) void*)l, 16, 0, 0);
}

// ===== merged preprocessing: [0,1024) doc_prep+hist-zero | [1024,3328) cvt_bt | [3328,3478) pw_ws =====
__global__ __launch_bounds__(256) void k_prep(const float* __restrict__ doc,
                                              const float* __restrict__ attn_w,
                                              const float* __restrict__ attn_b,
                                              unsigned short* __restrict__ docb,
                                              float* __restrict__ ewa,
                                              int* __restrict__ hist,
                                              const float* __restrict__ mlp1_w,
                                              unsigned short* __restrict__ Bt,
                                              const float* __restrict__ width_emb,
                                              const float* __restrict__ mlp1_b,
                                              float* __restrict__ PW,
                                              const float* __restrict__ wp_emb,
                                              const float* __restrict__ w1,
                                              const float* __restrict__ b1,
                                              const float* __restrict__ w2,
                                              const float* __restrict__ b2,
                                              float* __restrict__ wscore) {
    __shared__ float sh[32][33];
    __shared__ float red[256];
    int bx = blockIdx.x;
    int tid = threadIdx.x;
    if (bx < 1024) {
        // ---- doc_prep ----
        if (bx < 16) hist[bx * 256 + tid] = 0;
        int row = bx * 4 + (tid >> 6);
        int lane = tid & 63;
        const float* r = doc + (size_t)row * H;
        float s = 0.f;
        #pragma unroll
        for (int q = 0; q < 3; ++q) {
            int idx = q * 256 + lane * 4;
            float4 v = *reinterpret_cast<const float4*>(r + idx);
            float4 w = *reinterpret_cast<const float4*>(attn_w + idx);
            s += v.x * w.x + v.y * w.y + v.z * w.z + v.w * w.w;
            ushort4 o;
            o.x = f2bf(v.x); o.y = f2bf(v.y); o.z = f2bf(v.z); o.w = f2bf(v.w);
            *reinterpret_cast<ushort4*>(docb + (size_t)row * H + idx) = o;
        }
        #pragma unroll
        for (int off = 32; off > 0; off >>= 1) s += __shfl_down(s, off);
        if (lane == 0) ewa[row] = expf(s + attn_b[0]);
    } else if (bx < 3328) {
        // ---- cvt_bt ----
        int idx = bx - 1024;                    // 0..2303
        int k0 = (idx % 24) * 32;
        int m0 = ((idx / 24) % 32) * 32;
        int part = idx / (24 * 32);
        int rb = part == 0 ? 0 : (part == 1 ? H : (2 * H + E));
        int tx = tid & 31, ty = tid >> 5;
        #pragma unroll
        for (int it = 0; it < 4; ++it) {
            int kk = ty + it * 8;
            sh[kk][tx] = mlp1_w[(size_t)(rb + k0 + kk) * M + m0 + tx];
        }
        __syncthreads();
        #pragma unroll
        for (int it = 0; it < 4; ++it) {
            int mm = ty + it * 8;
            Bt[(size_t)(part * M + m0 + mm) * H + k0 + tx] = f2bf(sh[tx][mm]);
        }
    } else {
        // ---- pw_ws ----
        int idx = bx - 3328;                    // 0..149
        int w = idx / 5, y = idx % 5;
        if (y < 4) {
            int m = y * 256 + tid;
            float acc = mlp1_b[m];
            #pragma unroll
            for (int e = 0; e < E; ++e)
                acc += width_emb[w * E + e] * mlp1_w[(size_t)(2 * H + e) * M + m];
            PW[w * M + m] = acc;
        } else {
            float part = 0.f;
            for (int m = tid; m < M; m += 256) {
                float h = b1[m];
                #pragma unroll
                for (int e = 0; e < E; ++e) h += wp_emb[w * E + e] * w1[e * M + m];
                part += fmaxf(h, 0.f) * w2[m];
            }
            red[tid] = part;
            __syncthreads();
            for (int s = 128; s > 0; s >>= 1) {
                if (tid < s) red[tid] += red[tid + s];
                __syncthreads();
            }
            if (tid == 0) wscore[w] = red[0] + b2[0];
        }
    }
}

// ------- merged scans: block0 = Dpre from ewa; block1 = offs+begs from hist -------
__global__ __launch_bounds__(256) void k_scans2(const float* __restrict__ ewa,
                                                float* __restrict__ Dpre,
                                                const int* __restrict__ hist,
                                                int* __restrict__ offs,
                                                int* __restrict__ begs) {
    __shared__ float shf[256];
    __shared__ int shi[256];
    int t = threadIdx.x;
    if (blockIdx.x == 0) {
        float v[16];
        float sum = 0.f;
        #pragma unroll
        for (int i = 0; i < 16; ++i) { v[i] = ewa[t * 16 + i]; sum += v[i]; }
        shf[t] = sum;
        __syncthreads();
        for (int off = 1; off < 256; off <<= 1) {
            float x = (t >= off) ? shf[t - off] : 0.f;
            __syncthreads();
            shf[t] += x;
            __syncthreads();
        }
        float run = shf[t] - sum;
        #pragma unroll
        for (int i = 0; i < 16; ++i) { run += v[i]; Dpre[t * 16 + i + 1] = run; }
        if (t == 0) Dpre[0] = 0.f;
    } else {
        int v[16];
        int sum = 0;
        #pragma unroll
        for (int i = 0; i < 16; ++i) { v[i] = hist[t * 16 + i]; sum += v[i]; }
        shi[t] = sum;
        __syncthreads();
        for (int off = 1; off < 256; off <<= 1) {
            int x = (t >= off) ? shi[t - off] : 0;
            __syncthreads();
            shi[t] += x;
            __syncthreads();
        }
        int run = shi[t] - sum;
        #pragma unroll
        for (int i = 0; i < 16; ++i) {
            offs[t * 16 + i] = run;
            begs[t * 16 + i] = run;
            run += v[i];
        }
        if (t == 255) begs[4096] = run;   // == NC
    }
}

// ---------------- sort-by-start: hist / scatter ----------------
__global__ __launch_bounds__(256) void k_hist(const int* __restrict__ starts,
                                              int* __restrict__ hist) {
    atomicAdd(&hist[starts[blockIdx.x * 256 + threadIdx.x]], 1);
}
__global__ __launch_bounds__(256) void k_scatter(const int* __restrict__ starts,
                                                 int* __restrict__ offs,
                                                 int* __restrict__ perm) {
    int c = blockIdx.x * 256 + threadIdx.x;
    int p = atomicAdd(&offs[starts[c]], 1);
    perm[p] = c;
}

// ---------------- MFMA projection: 256x192 tile, 8 waves, 32x32x16 MFMA ----------
// Same r12 skeleton (dbuf, counted vmcnt(7), 1 blk/CU) but 32x32x16 MFMA: 2x FLOP
// per instruction from the same 16B/lane fragments -> MFMA instr/step halves and
// the 32x32 pipe is ~20% faster per FLOP (m119). Fragment-ordered LDS for the
// 32x32 layout: lane l <-> row (l&31), k-half (l>>5); linear 16B reads, 0 conflicts.
// C/D mapping (m74/m101): col=lane&31, row=(reg&3)+8*(reg>>2)+4*(lane>>5).
// Epilogue also emits chunk totals T (scan1 fused).
__global__ __launch_bounds__(512, 1) void k_proj_mfma(const unsigned short* __restrict__ docb,
                                                      const unsigned short* __restrict__ Bt,
                                                      const float* __restrict__ ewa,
                                                      unsigned short* __restrict__ Pse,
                                                      float* __restrict__ Sbuf,
                                                      float* __restrict__ T) {
    __shared__ unsigned short As[2][16384];  // [buf][mg32:8][ks:4][lane:64][j:8] 64KB
    __shared__ unsigned short Bs[2][12288];  // [buf][cg32:6][ks:4][lane:64][j:8] 48KB
    int tid = threadIdx.x;
    int bid = blockIdx.x;
    int xcd = bid & 7, rr0 = bid >> 3;
    int coltile = (xcd & 1) * 8 + (rr0 & 7);
    int rowtile = (xcd >> 1) * 4 + (rr0 >> 3);
    int col0 = coltile * 192;
    int row0 = rowtile * 256;
    int wv = tid >> 6, lane = tid & 63;
    int wr = wv >> 1, wc = wv & 1;              // 4M x 2N waves; wave tile 64x96

    f32x16 acc[2][3];
    #pragma unroll
    for (int mi = 0; mi < 2; ++mi)
        #pragma unroll
        for (int ni = 0; ni < 3; ++ni)
            #pragma unroll
            for (int j = 0; j < 16; ++j) acc[mi][ni][j] = 0.f;

    // 7 gload16 per thread per K-tile (4 A + 3 B) -> vmcnt(7) == prev tile landed
    #define STAGE(buf, k0)                                                            \
        {                                                                             \
            _Pragma("unroll")                                                         \
            for (int i = 0; i < 4; ++i) {                                             \
                int s = i * 512 + tid;                                                \
                int mg = s >> 8, ks = (s >> 6) & 3, l = s & 63;                       \
                gload16(docb + (size_t)(row0 + mg * 32 + (l & 31)) * H                \
                              + (k0) + ks * 16 + (l >> 5) * 8,                        \
                        (char*)As[buf] + s * 16);                                     \
            }                                                                         \
            _Pragma("unroll")                                                         \
            for (int i = 0; i < 3; ++i) {                                             \
                int s = i * 512 + tid;                                                \
                int cg = s >> 8, ks = (s >> 6) & 3, l = s & 63;                       \
                gload16(Bt + (size_t)(col0 + cg * 32 + (l & 31)) * H                  \
                            + (k0) + ks * 16 + (l >> 5) * 8,                          \
                        (char*)Bs[buf] + s * 16);                                     \
            }                                                                         \
        }

    STAGE(0, 0);
    STAGE(1, 64);
    asm volatile("s_waitcnt vmcnt(7)" ::: "memory");
    __builtin_amdgcn_s_barrier();

    #pragma unroll 1
    for (int t = 0; t < NKT; ++t) {
        int cur = t & 1;
        #pragma unroll
        for (int ks = 0; ks < 4; ++ks) {
            bf16x8 af[2], bfr[3];
            #pragma unroll
            for (int mi = 0; mi < 2; ++mi)
                af[mi] = *reinterpret_cast<const bf16x8*>(
                    (char*)As[cur] + (((wr * 2 + mi) * 4 + ks) * 64 + lane) * 16);
            #pragma unroll
            for (int ni = 0; ni < 3; ++ni)
                bfr[ni] = *reinterpret_cast<const bf16x8*>(
                    (char*)Bs[cur] + (((wc * 3 + ni) * 4 + ks) * 64 + lane) * 16);
            __builtin_amdgcn_s_setprio(1);
            #pragma unroll
            for (int mi = 0; mi < 2; ++mi)
                #pragma unroll
                for (int ni = 0; ni < 3; ++ni)
                    acc[mi][ni] = __builtin_amdgcn_mfma_f32_32x32x16_bf16(
                        af[mi], bfr[ni], acc[mi][ni], 0, 0, 0);
            __builtin_amdgcn_s_setprio(0);
        }
        if (t + 2 < NKT) {
            asm volatile("s_waitcnt lgkmcnt(0)" ::: "memory");  // all buf[cur] reads retired
            __builtin_amdgcn_sched_barrier(0);
            __builtin_amdgcn_s_barrier();                       // block-wide: buf[cur] free
            STAGE(cur, (t + 2) * 64);                           // overwrite buf[cur] w/ t+2
            asm volatile("s_waitcnt vmcnt(7)" ::: "memory");    // tile t+1 landed
            __builtin_amdgcn_s_barrier();                       // buf[cur^1] ready
        } else if (t + 2 == NKT) {
            asm volatile("s_waitcnt vmcnt(0)" ::: "memory");    // drain last tile
            __builtin_amdgcn_s_barrier();
        }
    }
    #undef STAGE

    int lcol = lane & 31;
    int lrh = lane >> 5;                         // row offset +4*lrh
    #pragma unroll
    for (int mi = 0; mi < 2; ++mi) {
        #pragma unroll
        for (int ni = 0; ni < 3; ++ni) {
            int cabs = col0 + wc * 96 + ni * 32 + lcol;
            int part = cabs >> 10;               // uniform per (wc,ni): 32-aligned tiles
            int cm = cabs & 1023;
            int rbase = row0 + wr * 64 + mi * 32 + 4 * lrh;
            if (part < 2) {
                #pragma unroll
                for (int reg = 0; reg < 16; ++reg) {
                    int r = rbase + (reg & 3) + 8 * (reg >> 2);
                    Pse[(size_t)r * 2048 + part * 1024 + cm] = f2bf(acc[mi][ni][reg]);
                }
            } else {
                #pragma unroll
                for (int reg = 0; reg < 16; ++reg) {
                    int r = rbase + (reg & 3) + 8 * (reg >> 2);
                    Sbuf[(size_t)r * M + cm] = acc[mi][ni][reg];
                }
            }
        }
    }
    // ---- chunk totals T (scan1 fused): wave's 64 rows = exactly one chunk ----
    {
        int chunk = (row0 >> 6) + wr;
        #pragma unroll
        for (int ni = 0; ni < 3; ++ni) {
            int cabs = col0 + wc * 96 + ni * 32 + lcol;
            if (cabs >= 2048) {
                float psum = 0.f;
                #pragma unroll
                for (int mi = 0; mi < 2; ++mi) {
                    int rbase = row0 + wr * 64 + mi * 32 + 4 * lrh;
                    #pragma unroll
                    for (int reg = 0; reg < 16; ++reg) {
                        int r = rbase + (reg & 3) + 8 * (reg >> 2);
                        psum += ewa[r] * acc[mi][ni][reg];
                    }
                }
                psum += __shfl_down(psum, 32);   // combine lrh=0/1 row halves
                if (lrh == 0)
                    T[(size_t)chunk * M + (cabs - 2048)] = psum;
            }
        }
    }
}

// ---------------- scan phase 2: exclusive scan of chunk totals (reg-resident) ----------------
__global__ __launch_bounds__(256) void k_scan2(float* __restrict__ T) {
    int m = blockIdx.x * 256 + threadIdx.x;
    float v[NCH];
    #pragma unroll
    for (int c = 0; c < NCH; ++c) v[c] = T[c * M + m];
    float run = 0.f;
    #pragma unroll
    for (int c = 0; c < NCH; ++c) { float t = v[c]; T[c * M + m] = run; run += t; }
}

// ---------------- scan phase 3: in-place inclusive prefix over Sbuf ----------------
__global__ __launch_bounds__(256) void k_scan3(float* __restrict__ Sbuf,
                                               const float* __restrict__ ewa,
                                               const float* __restrict__ T) {
    int m = blockIdx.x * 256 + threadIdx.x;
    int c = blockIdx.y;
    __shared__ float ew[CHUNK];
    if (threadIdx.x < CHUNK) ew[threadIdx.x] = ewa[c * CHUNK + threadIdx.x];
    __syncthreads();
    float acc = T[c * M + m];
    float* base = Sbuf + (size_t)(c * CHUNK) * M + m;
    #pragma unroll 4
    for (int i = 0; i < CHUNK; ++i) {
        float* p = base + (size_t)i * M;
        acc += ew[i] * (*p);
        *p = acc;
    }
}

// ---------------- per-START candidate scoring: one block per start value ----------------
__global__ __launch_bounds__(256) void k_cand(const unsigned short* __restrict__ Pse,
                                              const float* __restrict__ Sbuf,
                                              const float* __restrict__ PW,
                                              const float* __restrict__ Dpre,
                                              const float* __restrict__ wscore,
                                              const int* __restrict__ perm,
                                              const int* __restrict__ begs,
                                              const int* __restrict__ ends,
                                              const float* __restrict__ mlp2_w,
                                              const float* __restrict__ mlp2_b,
                                              float* __restrict__ out) {
    __shared__ __align__(16) unsigned short ps_l[1024];
    __shared__ __align__(16) float ss_l[1024];
    int bid = blockIdx.x;                           // 4096 blocks, %8==0 -> bijective
    int s = (bid & 7) * 512 + (bid >> 3);           // XCD-contiguous start ranges
    int tid = threadIdx.x;
    {
        ushort4 p4 = *reinterpret_cast<const ushort4*>(Pse + (size_t)s * 2048 + tid * 4);
        *reinterpret_cast<ushort4*>(ps_l + tid * 4) = p4;
        float4 s4 = (s > 0) ? *reinterpret_cast<const float4*>(Sbuf + (size_t)(s - 1) * M + tid * 4)
                            : make_float4(0.f, 0.f, 0.f, 0.f);
        *reinterpret_cast<float4*>(ss_l + tid * 4) = s4;
    }
    __syncthreads();
    int beg = begs[s], end = begs[s + 1];
    int wv = tid >> 6, lane = tid & 63;
    float dps = Dpre[s];
    // hoist candidate-invariant mlp2_w into registers
    float4 v00 = *reinterpret_cast<const float4*>(mlp2_w + lane * 8);
    float4 v01 = *reinterpret_cast<const float4*>(mlp2_w + lane * 8 + 4);
    float4 v10 = *reinterpret_cast<const float4*>(mlp2_w + lane * 8 + 512);
    float4 v11 = *reinterpret_cast<const float4*>(mlp2_w + lane * 8 + 516);

    for (int j = beg + wv; j < end; j += 4) {
        int c = perm[j];
        int e = ends[c];
        int wi = e - s;
        wi = wi > MSW - 1 ? MSW - 1 : wi;
        float inv = 1.f / (Dpre[e + 1] - dps);
        const unsigned short* pe = Pse + (size_t)e * 2048 + 1024;
        const float* se = Sbuf + (size_t)e * M;
        const float* pw = PW + (size_t)wi * M;

        float part = 0.f;
        #pragma unroll
        for (int q = 0; q < 2; ++q) {
            int m = lane * 8 + q * 512;
            u16x8 a8 = *reinterpret_cast<const u16x8*>(ps_l + m);
            u16x8 b8 = *reinterpret_cast<const u16x8*>(pe + m);
            float4 t0 = *reinterpret_cast<const float4*>(se + m);
            float4 t1 = *reinterpret_cast<const float4*>(se + m + 4);
            float4 u0 = *reinterpret_cast<const float4*>(ss_l + m);
            float4 u1 = *reinterpret_cast<const float4*>(ss_l + m + 4);
            float4 w0 = *reinterpret_cast<const float4*>(pw + m);
            float4 w1 = *reinterpret_cast<const float4*>(pw + m + 4);
            float4 v0 = q ? v10 : v00;
            float4 v1 = q ? v11 : v01;
            float x;
            x = bf2f(a8[0]) + bf2f(b8[0]) + w0.x + (t0.x - u0.x) * inv; part += fmaxf(x, 0.f) * v0.x;
            x = bf2f(a8[1]) + bf2f(b8[1]) + w0.y + (t0.y - u0.y) * inv; part += fmaxf(x, 0.f) * v0.y;
            x = bf2f(a8[2]) + bf2f(b8[2]) + w0.z + (t0.z - u0.z) * inv; part += fmaxf(x, 0.f) * v0.z;
            x = bf2f(a8[3]) + bf2f(b8[3]) + w0.w + (t0.w - u0.w) * inv; part += fmaxf(x, 0.f) * v0.w;
            x = bf2f(a8[4]) + bf2f(b8[4]) + w1.x + (t1.x - u1.x) * inv; part += fmaxf(x, 0.f) * v1.x;
            x = bf2f(a8[5]) + bf2f(b8[5]) + w1.y + (t1.y - u1.y) * inv; part += fmaxf(x, 0.f) * v1.y;
            x = bf2f(a8[6]) + bf2f(b8[6]) + w1.z + (t1.z - u1.z) * inv; part += fmaxf(x, 0.f) * v1.z;
            x = bf2f(a8[7]) + bf2f(b8[7]) + w1.w + (t1.w - u1.w) * inv; part += fmaxf(x, 0.f) * v1.w;
        }
        #pragma unroll
        for (int off = 32; off > 0; off >>= 1) part += __shfl_down(part, off);
        if (lane == 0) out[c] = part + mlp2_b[0] + wscore[wi];
    }
}

extern "C" void kernel_launch(void* const* d_in, const int* in_sizes, int n_in,
                              void* d_out, int out_size, void* d_ws, size_t ws_size,
                              hipStream_t stream) {
    const float* encoded_doc = (const float*)d_in[0];
    const int*   cand_starts = (const int*)d_in[1];
    const int*   cand_ends   = (const int*)d_in[2];
    const float* width_emb   = (const float*)d_in[3];
    const float* width_prior = (const float*)d_in[4];
    const float* attn_w      = (const float*)d_in[5];
    const float* attn_b      = (const float*)d_in[6];
    const float* mlp1_w      = (const float*)d_in[7];
    const float* mlp1_b      = (const float*)d_in[8];
    const float* mlp2_w      = (const float*)d_in[9];
    const float* mlp2_b      = (const float*)d_in[10];
    const float* wmlp1_w     = (const float*)d_in[11];
    const float* wmlp1_b     = (const float*)d_in[12];
    const float* wmlp2_w     = (const float*)d_in[13];
    const float* wmlp2_b     = (const float*)d_in[14];
    float* out = (float*)d_out;

    // workspace layout (float units from base; all large blocks 16B-aligned)
    float* Sbuf   = (float*)d_ws;                      // NW*1024
    float* T      = Sbuf + (size_t)NW * M;             // NCH*M = 65536
    float* PW     = T + NCH * M;                       // 30*1024
    float* ewa    = PW + MSW * M;                      // 4096
    float* Dpre   = ewa + NW;                          // 4160
    float* wscore = Dpre + 4160;                       // 64
    unsigned short* Pse  = (unsigned short*)(wscore + 64);      // NW*2048 bf16
    unsigned short* docb = Pse + (size_t)NW * 2048;             // NW*H bf16
    unsigned short* Btb  = docb + (size_t)NW * H;               // 3072*H bf16
    int* hist = (int*)(Btb + (size_t)3072 * H);        // 4096
    int* offs = hist + 4096;                           // 4096
    int* begs = offs + 4096;                           // 4097 (pad 4112)
    int* perm = begs + 4112;                           // NC

    k_prep<<<3478, 256, 0, stream>>>(encoded_doc, attn_w, attn_b, docb, ewa, hist,
                                     mlp1_w, Btb, width_emb, mlp1_b, PW,
                                     width_prior, wmlp1_w, wmlp1_b, wmlp2_w, wmlp2_b, wscore);
    k_hist<<<NC / 256, 256, 0, stream>>>(cand_starts, hist);
    k_scans2<<<2, 256, 0, stream>>>(ewa, Dpre, hist, offs, begs);
    k_scatter<<<NC / 256, 256, 0, stream>>>(cand_starts, offs, perm);
    k_proj_mfma<<<256, 512, 0, stream>>>(docb, Btb, ewa, Pse, Sbuf, T);
    k_scan2<<<M / 256, 256, 0, stream>>>(T);
    k_scan3<<<dim3(M / 256, NCH), 256, 0, stream>>>(Sbuf, ewa, T);
    k_cand<<<4096, 256, 0, stream>>>(Pse, Sbuf, PW, Dpre, wscore, perm, begs,
                                     cand_ends, mlp2_w, mlp2_b, out);
}

// Round 16
// 109.661 us; speedup vs baseline: 1.1602x; 1.0154x over previous
//
#include <hip/hip_runtime.h>
#include <math.h>

#define NW 4096
#define H 768
#define NC 49152
#define MSW 30
#define E 20
#define M 1024
#define CHUNK 64
#define NCH (NW / CHUNK)
#define NKT (H / 64)   // 12 K-tiles of 64
// Pse: bf16 [NW][2048] (cols 0:1024 start-proj, 1024:2048 end-proj)
// Sbuf: f32 [NW][1024] attn-proj, overwritten in place by exp-weighted prefix:
//   Sbuf[r][m] = S[r+1][m] = sum_{i<=r} ewa[i]*Pattn[i][m]

typedef short bf16x8 __attribute__((ext_vector_type(8)));
typedef unsigned short u16x8 __attribute__((ext_vector_type(8)));
typedef float f32x4 __attribute__((ext_vector_type(4)));

__device__ __forceinline__ unsigned short f2bf(float x) {
    unsigned u = __float_as_uint(x);
    return (unsigned short)((u + 0x7fff + ((u >> 16) & 1)) >> 16);  // RNE
}
__device__ __forceinline__ float bf2f(unsigned short b) {
    return __uint_as_float(((unsigned)b) << 16);
}
__device__ __forceinline__ void gload16(const void* g, void* l) {
    __builtin_amdgcn_global_load_lds((const __attribute__((address_space(1))) void*)g,
                                     (__attribute__((address_space(3))) void*)l, 16, 0, 0);
}

// ===== merged preprocessing: [0,1024) doc_prep+hist-zero | [1024,3328) cvt_bt | [3328,3478) pw_ws =====
__global__ __launch_bounds__(256) void k_prep(const float* __restrict__ doc,
                                              const float* __restrict__ attn_w,
                                              const float* __restrict__ attn_b,
                                              unsigned short* __restrict__ docb,
                                              float* __restrict__ ewa,
                                              int* __restrict__ hist,
                                              const float* __restrict__ mlp1_w,
                                              unsigned short* __restrict__ Bt,
                                              const float* __restrict__ width_emb,
                                              const float* __restrict__ mlp1_b,
                                              float* __restrict__ PW,
                                              const float* __restrict__ wp_emb,
                                              const float* __restrict__ w1,
                                              const float* __restrict__ b1,
                                              const float* __restrict__ w2,
                                              const float* __restrict__ b2,
                                              float* __restrict__ wscore) {
    __shared__ float sh[32][33];
    __shared__ float red[256];
    int bx = blockIdx.x;
    int tid = threadIdx.x;
    if (bx < 1024) {
        // ---- doc_prep ----
        if (bx < 16) hist[bx * 256 + tid] = 0;
        int row = bx * 4 + (tid >> 6);
        int lane = tid & 63;
        const float* r = doc + (size_t)row * H;
        float s = 0.f;
        #pragma unroll
        for (int q = 0; q < 3; ++q) {
            int idx = q * 256 + lane * 4;
            float4 v = *reinterpret_cast<const float4*>(r + idx);
            float4 w = *reinterpret_cast<const float4*>(attn_w + idx);
            s += v.x * w.x + v.y * w.y + v.z * w.z + v.w * w.w;
            ushort4 o;
            o.x = f2bf(v.x); o.y = f2bf(v.y); o.z = f2bf(v.z); o.w = f2bf(v.w);
            *reinterpret_cast<ushort4*>(docb + (size_t)row * H + idx) = o;
        }
        #pragma unroll
        for (int off = 32; off > 0; off >>= 1) s += __shfl_down(s, off);
        if (lane == 0) ewa[row] = expf(s + attn_b[0]);
    } else if (bx < 3328) {
        // ---- cvt_bt ----
        int idx = bx - 1024;                    // 0..2303
        int k0 = (idx % 24) * 32;
        int m0 = ((idx / 24) % 32) * 32;
        int part = idx / (24 * 32);
        int rb = part == 0 ? 0 : (part == 1 ? H : (2 * H + E));
        int tx = tid & 31, ty = tid >> 5;
        #pragma unroll
        for (int it = 0; it < 4; ++it) {
            int kk = ty + it * 8;
            sh[kk][tx] = mlp1_w[(size_t)(rb + k0 + kk) * M + m0 + tx];
        }
        __syncthreads();
        #pragma unroll
        for (int it = 0; it < 4; ++it) {
            int mm = ty + it * 8;
            Bt[(size_t)(part * M + m0 + mm) * H + k0 + tx] = f2bf(sh[tx][mm]);
        }
    } else {
        // ---- pw_ws ----
        int idx = bx - 3328;                    // 0..149
        int w = idx / 5, y = idx % 5;
        if (y < 4) {
            int m = y * 256 + tid;
            float acc = mlp1_b[m];
            #pragma unroll
            for (int e = 0; e < E; ++e)
                acc += width_emb[w * E + e] * mlp1_w[(size_t)(2 * H + e) * M + m];
            PW[w * M + m] = acc;
        } else {
            float part = 0.f;
            for (int m = tid; m < M; m += 256) {
                float h = b1[m];
                #pragma unroll
                for (int e = 0; e < E; ++e) h += wp_emb[w * E + e] * w1[e * M + m];
                part += fmaxf(h, 0.f) * w2[m];
            }
            red[tid] = part;
            __syncthreads();
            for (int s = 128; s > 0; s >>= 1) {
                if (tid < s) red[tid] += red[tid + s];
                __syncthreads();
            }
            if (tid == 0) wscore[w] = red[0] + b2[0];
        }
    }
}

// ------- merged scans: block0 = Dpre from ewa; block1 = offs+begs from hist -------
__global__ __launch_bounds__(256) void k_scans2(const float* __restrict__ ewa,
                                                float* __restrict__ Dpre,
                                                const int* __restrict__ hist,
                                                int* __restrict__ offs,
                                                int* __restrict__ begs) {
    __shared__ float shf[256];
    __shared__ int shi[256];
    int t = threadIdx.x;
    if (blockIdx.x == 0) {
        float v[16];
        float sum = 0.f;
        #pragma unroll
        for (int i = 0; i < 16; ++i) { v[i] = ewa[t * 16 + i]; sum += v[i]; }
        shf[t] = sum;
        __syncthreads();
        for (int off = 1; off < 256; off <<= 1) {
            float x = (t >= off) ? shf[t - off] : 0.f;
            __syncthreads();
            shf[t] += x;
            __syncthreads();
        }
        float run = shf[t] - sum;
        #pragma unroll
        for (int i = 0; i < 16; ++i) { run += v[i]; Dpre[t * 16 + i + 1] = run; }
        if (t == 0) Dpre[0] = 0.f;
    } else {
        int v[16];
        int sum = 0;
        #pragma unroll
        for (int i = 0; i < 16; ++i) { v[i] = hist[t * 16 + i]; sum += v[i]; }
        shi[t] = sum;
        __syncthreads();
        for (int off = 1; off < 256; off <<= 1) {
            int x = (t >= off) ? shi[t - off] : 0;
            __syncthreads();
            shi[t] += x;
            __syncthreads();
        }
        int run = shi[t] - sum;
        #pragma unroll
        for (int i = 0; i < 16; ++i) {
            offs[t * 16 + i] = run;
            begs[t * 16 + i] = run;
            run += v[i];
        }
        if (t == 255) begs[4096] = run;   // == NC
    }
}

// ---------------- sort-by-start: hist / scatter ----------------
__global__ __launch_bounds__(256) void k_hist(const int* __restrict__ starts,
                                              int* __restrict__ hist) {
    atomicAdd(&hist[starts[blockIdx.x * 256 + threadIdx.x]], 1);
}
__global__ __launch_bounds__(256) void k_scatter(const int* __restrict__ starts,
                                                 int* __restrict__ offs,
                                                 int* __restrict__ perm) {
    int c = blockIdx.x * 256 + threadIdx.x;
    int p = atomicAdd(&offs[starts[c]], 1);
    perm[p] = c;
}

// ---------------- MFMA projection: 128x192 tile, 8 waves, 2 BLOCKS/CU ----------------
// Single-variable test vs r12: 80KB LDS -> 2 co-resident blocks/CU (16 waves/CU) so
// one block's MFMA cluster hides the other's stage/barrier drain (m114 overlap).
// Fragment-ordered LDS (linear ds_reads, 0 conflicts), counted vmcnt(5) 2-deep
// pipeline. Epilogue emits chunk totals T (scan1 fused).
__global__ __launch_bounds__(512, 4) void k_proj_mfma(const unsigned short* __restrict__ docb,
                                                      const unsigned short* __restrict__ Bt,
                                                      const float* __restrict__ ewa,
                                                      unsigned short* __restrict__ Pse,
                                                      float* __restrict__ Sbuf,
                                                      float* __restrict__ T) {
    __shared__ unsigned short As[2][8192];   // [buf][mg:8][ks:2][g:4][ri:16][j:8] 32KB
    __shared__ unsigned short Bs[2][12288];  // [buf][cg:12][ks:2][g:4][ci:16][j:8] 48KB
    int tid = threadIdx.x;
    // XCD-bijective supertile map (512 blocks = 64/XCD): 8 col-tiles x 8 row-tiles
    // -> footprint 2.36MB Bt + 1.57MB docb = 3.9MB < 4MB L2.
    int bid = blockIdx.x;
    int xcd = bid & 7, rr0 = bid >> 3;              // rr0: 0..63
    int coltile = (xcd & 1) * 8 + (rr0 & 7);        // 0..15
    int rowtile = (xcd >> 1) * 8 + (rr0 >> 3);      // 0..31
    int col0 = coltile * 192;
    int row0 = rowtile * 128;
    int wv = tid >> 6, lane = tid & 63;
    int wr = wv >> 2, wc = wv & 3;                  // 2M x 4N waves; wave tile 64x48

    f32x4 acc[4][3];
    #pragma unroll
    for (int mi = 0; mi < 4; ++mi)
        #pragma unroll
        for (int ni = 0; ni < 3; ++ni) acc[mi][ni] = (f32x4){0.f, 0.f, 0.f, 0.f};

    // 5 gload16 per thread per K-tile (2 A + 3 B) -> vmcnt(5) == prev tile landed
    #define STAGE(buf, k0)                                                            \
        {                                                                             \
            _Pragma("unroll")                                                         \
            for (int i = 0; i < 2; ++i) {                                             \
                int s = i * 512 + tid;                                                \
                int mg = s >> 7, ks = (s >> 6) & 1, g = (s >> 4) & 3, ri = s & 15;    \
                gload16(docb + (size_t)(row0 + mg * 16 + ri) * H + (k0) + ks * 32 + g * 8, \
                        (char*)As[buf] + s * 16);                                     \
            }                                                                         \
            _Pragma("unroll")                                                         \
            for (int i = 0; i < 3; ++i) {                                             \
                int s = i * 512 + tid;                                                \
                int cg = s >> 7, ks = (s >> 6) & 1, g = (s >> 4) & 3, ci = s & 15;    \
                gload16(Bt + (size_t)(col0 + cg * 16 + ci) * H + (k0) + ks * 32 + g * 8, \
                        (char*)Bs[buf] + s * 16);                                     \
            }                                                                         \
        }

    STAGE(0, 0);
    STAGE(1, 64);
    asm volatile("s_waitcnt vmcnt(5)" ::: "memory");  // tile 0 landed (tile 1 in flight)
    __builtin_amdgcn_s_barrier();

    #pragma unroll 1
    for (int t = 0; t < NKT; ++t) {
        int cur = t & 1;
        #pragma unroll
        for (int ks = 0; ks < 2; ++ks) {
            bf16x8 af[4], bfr[3];
            #pragma unroll
            for (int mi = 0; mi < 4; ++mi)
                af[mi] = *reinterpret_cast<const bf16x8*>(
                    (char*)As[cur] + (wr * 4 + mi) * 2048 + ks * 1024 + lane * 16);
            #pragma unroll
            for (int ni = 0; ni < 3; ++ni)
                bfr[ni] = *reinterpret_cast<const bf16x8*>(
                    (char*)Bs[cur] + (wc * 3 + ni) * 2048 + ks * 1024 + lane * 16);
            __builtin_amdgcn_s_setprio(1);
            #pragma unroll
            for (int mi = 0; mi < 4; ++mi)
                #pragma unroll
                for (int ni = 0; ni < 3; ++ni)
                    acc[mi][ni] = __builtin_amdgcn_mfma_f32_16x16x32_bf16(
                        af[mi], bfr[ni], acc[mi][ni], 0, 0, 0);
            __builtin_amdgcn_s_setprio(0);
        }
        if (t + 2 < NKT) {
            asm volatile("s_waitcnt lgkmcnt(0)" ::: "memory");  // all buf[cur] reads retired
            __builtin_amdgcn_sched_barrier(0);
            __builtin_amdgcn_s_barrier();                       // block-wide: buf[cur] free
            STAGE(cur, (t + 2) * 64);                           // overwrite buf[cur] w/ t+2
            asm volatile("s_waitcnt vmcnt(5)" ::: "memory");    // tile t+1 landed
            __builtin_amdgcn_s_barrier();                       // buf[cur^1] ready
        } else if (t + 2 == NKT) {
            asm volatile("s_waitcnt vmcnt(0)" ::: "memory");    // drain last tile
            __builtin_amdgcn_s_barrier();
        }
    }
    #undef STAGE

    int cr = (lane >> 4) * 4;
    int cc = lane & 15;
    #pragma unroll
    for (int mi = 0; mi < 4; ++mi) {
        #pragma unroll
        for (int ni = 0; ni < 3; ++ni) {
            int rrow = row0 + wr * 64 + mi * 16 + cr;
            int cabs = col0 + wc * 48 + ni * 16 + cc;
            int part = cabs >> 10;
            int cm = cabs & 1023;
            if (part < 2) {
                unsigned short* dst = Pse + (size_t)rrow * 2048 + part * 1024 + cm;
                #pragma unroll
                for (int j = 0; j < 4; ++j) dst[(size_t)j * 2048] = f2bf(acc[mi][ni][j]);
            } else {
                float* dst = Sbuf + (size_t)rrow * M + cm;
                #pragma unroll
                for (int j = 0; j < 4; ++j) dst[(size_t)j * M] = acc[mi][ni][j];
            }
        }
    }
    // ---- chunk totals T (scan1 fused): each wave's 64 rows = exactly one chunk ----
    {
        int chunk = (row0 >> 6) + wr;
        #pragma unroll
        for (int ni = 0; ni < 3; ++ni) {
            int cabs = col0 + wc * 48 + ni * 16 + cc;
            if (cabs >= 2048) {
                float psum = 0.f;
                #pragma unroll
                for (int mi = 0; mi < 4; ++mi) {
                    int rbase = row0 + wr * 64 + mi * 16 + cr;
                    #pragma unroll
                    for (int j = 0; j < 4; ++j)
                        psum += ewa[rbase + j] * acc[mi][ni][j];
                }
                psum += __shfl_down(psum, 16);
                psum += __shfl_down(psum, 32);
                if ((lane >> 4) == 0)
                    T[(size_t)chunk * M + (cabs - 2048)] = psum;
            }
        }
    }
}

// ---------------- scan phase 2: exclusive scan of chunk totals (reg-resident) ----------------
__global__ __launch_bounds__(256) void k_scan2(float* __restrict__ T) {
    int m = blockIdx.x * 256 + threadIdx.x;
    float v[NCH];
    #pragma unroll
    for (int c = 0; c < NCH; ++c) v[c] = T[c * M + m];
    float run = 0.f;
    #pragma unroll
    for (int c = 0; c < NCH; ++c) { float t = v[c]; T[c * M + m] = run; run += t; }
}

// ---------------- scan phase 3: in-place inclusive prefix over Sbuf ----------------
__global__ __launch_bounds__(256) void k_scan3(float* __restrict__ Sbuf,
                                               const float* __restrict__ ewa,
                                               const float* __restrict__ T) {
    int m = blockIdx.x * 256 + threadIdx.x;
    int c = blockIdx.y;
    __shared__ float ew[CHUNK];
    if (threadIdx.x < CHUNK) ew[threadIdx.x] = ewa[c * CHUNK + threadIdx.x];
    __syncthreads();
    float acc = T[c * M + m];
    float* base = Sbuf + (size_t)(c * CHUNK) * M + m;
    #pragma unroll 4
    for (int i = 0; i < CHUNK; ++i) {
        float* p = base + (size_t)i * M;
        acc += ew[i] * (*p);
        *p = acc;
    }
}

// ---------------- per-START candidate scoring: one block per start value ----------------
__global__ __launch_bounds__(256) void k_cand(const unsigned short* __restrict__ Pse,
                                              const float* __restrict__ Sbuf,
                                              const float* __restrict__ PW,
                                              const float* __restrict__ Dpre,
                                              const float* __restrict__ wscore,
                                              const int* __restrict__ perm,
                                              const int* __restrict__ begs,
                                              const int* __restrict__ ends,
                                              const float* __restrict__ mlp2_w,
                                              const float* __restrict__ mlp2_b,
                                              float* __restrict__ out) {
    __shared__ __align__(16) unsigned short ps_l[1024];
    __shared__ __align__(16) float ss_l[1024];
    int bid = blockIdx.x;                           // 4096 blocks, %8==0 -> bijective
    int s = (bid & 7) * 512 + (bid >> 3);           // XCD-contiguous start ranges
    int tid = threadIdx.x;
    {
        ushort4 p4 = *reinterpret_cast<const ushort4*>(Pse + (size_t)s * 2048 + tid * 4);
        *reinterpret_cast<ushort4*>(ps_l + tid * 4) = p4;
        float4 s4 = (s > 0) ? *reinterpret_cast<const float4*>(Sbuf + (size_t)(s - 1) * M + tid * 4)
                            : make_float4(0.f, 0.f, 0.f, 0.f);
        *reinterpret_cast<float4*>(ss_l + tid * 4) = s4;
    }
    __syncthreads();
    int beg = begs[s], end = begs[s + 1];
    int wv = tid >> 6, lane = tid & 63;
    float dps = Dpre[s];
    // hoist candidate-invariant mlp2_w into registers
    float4 v00 = *reinterpret_cast<const float4*>(mlp2_w + lane * 8);
    float4 v01 = *reinterpret_cast<const float4*>(mlp2_w + lane * 8 + 4);
    float4 v10 = *reinterpret_cast<const float4*>(mlp2_w + lane * 8 + 512);
    float4 v11 = *reinterpret_cast<const float4*>(mlp2_w + lane * 8 + 516);

    for (int j = beg + wv; j < end; j += 4) {
        int c = perm[j];
        int e = ends[c];
        int wi = e - s;
        wi = wi > MSW - 1 ? MSW - 1 : wi;
        float inv = 1.f / (Dpre[e + 1] - dps);
        const unsigned short* pe = Pse + (size_t)e * 2048 + 1024;
        const float* se = Sbuf + (size_t)e * M;
        const float* pw = PW + (size_t)wi * M;

        float part = 0.f;
        #pragma unroll
        for (int q = 0; q < 2; ++q) {
            int m = lane * 8 + q * 512;
            u16x8 a8 = *reinterpret_cast<const u16x8*>(ps_l + m);
            u16x8 b8 = *reinterpret_cast<const u16x8*>(pe + m);
            float4 t0 = *reinterpret_cast<const float4*>(se + m);
            float4 t1 = *reinterpret_cast<const float4*>(se + m + 4);
            float4 u0 = *reinterpret_cast<const float4*>(ss_l + m);
            float4 u1 = *reinterpret_cast<const float4*>(ss_l + m + 4);
            float4 w0 = *reinterpret_cast<const float4*>(pw + m);
            float4 w1 = *reinterpret_cast<const float4*>(pw + m + 4);
            float4 v0 = q ? v10 : v00;
            float4 v1 = q ? v11 : v01;
            float x;
            x = bf2f(a8[0]) + bf2f(b8[0]) + w0.x + (t0.x - u0.x) * inv; part += fmaxf(x, 0.f) * v0.x;
            x = bf2f(a8[1]) + bf2f(b8[1]) + w0.y + (t0.y - u0.y) * inv; part += fmaxf(x, 0.f) * v0.y;
            x = bf2f(a8[2]) + bf2f(b8[2]) + w0.z + (t0.z - u0.z) * inv; part += fmaxf(x, 0.f) * v0.z;
            x = bf2f(a8[3]) + bf2f(b8[3]) + w0.w + (t0.w - u0.w) * inv; part += fmaxf(x, 0.f) * v0.w;
            x = bf2f(a8[4]) + bf2f(b8[4]) + w1.x + (t1.x - u1.x) * inv; part += fmaxf(x, 0.f) * v1.x;
            x = bf2f(a8[5]) + bf2f(b8[5]) + w1.y + (t1.y - u1.y) * inv; part += fmaxf(x, 0.f) * v1.y;
            x = bf2f(a8[6]) + bf2f(b8[6]) + w1.z + (t1.z - u1.z) * inv; part += fmaxf(x, 0.f) * v1.z;
            x = bf2f(a8[7]) + bf2f(b8[7]) + w1.w + (t1.w - u1.w) * inv; part += fmaxf(x, 0.f) * v1.w;
        }
        #pragma unroll
        for (int off = 32; off > 0; off >>= 1) part += __shfl_down(part, off);
        if (lane == 0) out[c] = part + mlp2_b[0] + wscore[wi];
    }
}

extern "C" void kernel_launch(void* const* d_in, const int* in_sizes, int n_in,
                              void* d_out, int out_size, void* d_ws, size_t ws_size,
                              hipStream_t stream) {
    const float* encoded_doc = (const float*)d_in[0];
    const int*   cand_starts = (const int*)d_in[1];
    const int*   cand_ends   = (const int*)d_in[2];
    const float* width_emb   = (const float*)d_in[3];
    const float* width_prior = (const float*)d_in[4];
    const float* attn_w      = (const float*)d_in[5];
    const float* attn_b      = (const float*)d_in[6];
    const float* mlp1_w      = (const float*)d_in[7];
    const float* mlp1_b      = (const float*)d_in[8];
    const float* mlp2_w      = (const float*)d_in[9];
    const float* mlp2_b      = (const float*)d_in[10];
    const float* wmlp1_w     = (const float*)d_in[11];
    const float* wmlp1_b     = (const float*)d_in[12];
    const float* wmlp2_w     = (const float*)d_in[13];
    const float* wmlp2_b     = (const float*)d_in[14];
    float* out = (float*)d_out;

    // workspace layout (float units from base; all large blocks 16B-aligned)
    float* Sbuf   = (float*)d_ws;                      // NW*1024
    float* T      = Sbuf + (size_t)NW * M;             // NCH*M = 65536
    float* PW     = T + NCH * M;                       // 30*1024
    float* ewa    = PW + MSW * M;                      // 4096
    float* Dpre   = ewa + NW;                          // 4160
    float* wscore = Dpre + 4160;                       // 64
    unsigned short* Pse  = (unsigned short*)(wscore + 64);      // NW*2048 bf16
    unsigned short* docb = Pse + (size_t)NW * 2048;             // NW*H bf16
    unsigned short* Btb  = docb + (size_t)NW * H;               // 3072*H bf16
    int* hist = (int*)(Btb + (size_t)3072 * H);        // 4096
    int* offs = hist + 4096;                           // 4096
    int* begs = offs + 4096;                           // 4097 (pad 4112)
    int* perm = begs + 4112;                           // NC

    k_prep<<<3478, 256, 0, stream>>>(encoded_doc, attn_w, attn_b, docb, ewa, hist,
                                     mlp1_w, Btb, width_emb, mlp1_b, PW,
                                     width_prior, wmlp1_w, wmlp1_b, wmlp2_w, wmlp2_b, wscore);
    k_hist<<<NC / 256, 256, 0, stream>>>(cand_starts, hist);
    k_scans2<<<2, 256, 0, stream>>>(ewa, Dpre, hist, offs, begs);
    k_scatter<<<NC / 256, 256, 0, stream>>>(cand_starts, offs, perm);
    k_proj_mfma<<<512, 512, 0, stream>>>(docb, Btb, ewa, Pse, Sbuf, T);
    k_scan2<<<M / 256, 256, 0, stream>>>(T);
    k_scan3<<<dim3(M / 256, NCH), 256, 0, stream>>>(Sbuf, ewa, T);
    k_cand<<<4096, 256, 0, stream>>>(Pse, Sbuf, PW, Dpre, wscore, perm, begs,
                                     cand_ends, mlp2_w, mlp2_b, out);
}

// Round 17
// 108.204 us; speedup vs baseline: 1.1758x; 1.0135x over previous
//
#include <hip/hip_runtime.h>
#include <math.h>

#define NW 4096
#define H 768
#define NC 49152
#define MSW 30
#define E 20
#define M 1024
#define CHUNK 64
#define NCH (NW / CHUNK)
#define NKT (H / 64)   // 12 K-tiles of 64
// Pse: bf16 [NW][2048] (cols 0:1024 start-proj, 1024:2048 end-proj)
// Sbuf: f32 [NW][1024] attn-proj, overwritten in place by exp-weighted prefix:
//   Sbuf[r][m] = S[r+1][m] = sum_{i<=r} ewa[i]*Pattn[i][m]
// PW: bf16 [MSW][1024] (r17: was f32; values ~1e-2, bf16 error negligible)

typedef short bf16x8 __attribute__((ext_vector_type(8)));
typedef unsigned short u16x8 __attribute__((ext_vector_type(8)));
typedef float f32x4 __attribute__((ext_vector_type(4)));

__device__ __forceinline__ unsigned short f2bf(float x) {
    unsigned u = __float_as_uint(x);
    return (unsigned short)((u + 0x7fff + ((u >> 16) & 1)) >> 16);  // RNE
}
__device__ __forceinline__ float bf2f(unsigned short b) {
    return __uint_as_float(((unsigned)b) << 16);
}
__device__ __forceinline__ void gload16(const void* g, void* l) {
    __builtin_amdgcn_global_load_lds((const __attribute__((address_space(1))) void*)g,
                                     (__attribute__((address_space(3))) void*)l, 16, 0, 0);
}

// ===== merged preprocessing: [0,1024) doc_prep+hist-zero | [1024,3328) cvt_bt | [3328,3478) pw_ws =====
__global__ __launch_bounds__(256) void k_prep(const float* __restrict__ doc,
                                              const float* __restrict__ attn_w,
                                              const float* __restrict__ attn_b,
                                              unsigned short* __restrict__ docb,
                                              float* __restrict__ ewa,
                                              int* __restrict__ hist,
                                              const float* __restrict__ mlp1_w,
                                              unsigned short* __restrict__ Bt,
                                              const float* __restrict__ width_emb,
                                              const float* __restrict__ mlp1_b,
                                              unsigned short* __restrict__ PW,
                                              const float* __restrict__ wp_emb,
                                              const float* __restrict__ w1,
                                              const float* __restrict__ b1,
                                              const float* __restrict__ w2,
                                              const float* __restrict__ b2,
                                              float* __restrict__ wscore) {
    __shared__ float sh[32][33];
    __shared__ float red[256];
    int bx = blockIdx.x;
    int tid = threadIdx.x;
    if (bx < 1024) {
        // ---- doc_prep ----
        if (bx < 16) hist[bx * 256 + tid] = 0;
        int row = bx * 4 + (tid >> 6);
        int lane = tid & 63;
        const float* r = doc + (size_t)row * H;
        float s = 0.f;
        #pragma unroll
        for (int q = 0; q < 3; ++q) {
            int idx = q * 256 + lane * 4;
            float4 v = *reinterpret_cast<const float4*>(r + idx);
            float4 w = *reinterpret_cast<const float4*>(attn_w + idx);
            s += v.x * w.x + v.y * w.y + v.z * w.z + v.w * w.w;
            ushort4 o;
            o.x = f2bf(v.x); o.y = f2bf(v.y); o.z = f2bf(v.z); o.w = f2bf(v.w);
            *reinterpret_cast<ushort4*>(docb + (size_t)row * H + idx) = o;
        }
        #pragma unroll
        for (int off = 32; off > 0; off >>= 1) s += __shfl_down(s, off);
        if (lane == 0) ewa[row] = expf(s + attn_b[0]);
    } else if (bx < 3328) {
        // ---- cvt_bt ----
        int idx = bx - 1024;                    // 0..2303
        int k0 = (idx % 24) * 32;
        int m0 = ((idx / 24) % 32) * 32;
        int part = idx / (24 * 32);
        int rb = part == 0 ? 0 : (part == 1 ? H : (2 * H + E));
        int tx = tid & 31, ty = tid >> 5;
        #pragma unroll
        for (int it = 0; it < 4; ++it) {
            int kk = ty + it * 8;
            sh[kk][tx] = mlp1_w[(size_t)(rb + k0 + kk) * M + m0 + tx];
        }
        __syncthreads();
        #pragma unroll
        for (int it = 0; it < 4; ++it) {
            int mm = ty + it * 8;
            Bt[(size_t)(part * M + m0 + mm) * H + k0 + tx] = f2bf(sh[tx][mm]);
        }
    } else {
        // ---- pw_ws ----
        int idx = bx - 3328;                    // 0..149
        int w = idx / 5, y = idx % 5;
        if (y < 4) {
            int m = y * 256 + tid;
            float acc = mlp1_b[m];
            #pragma unroll
            for (int e = 0; e < E; ++e)
                acc += width_emb[w * E + e] * mlp1_w[(size_t)(2 * H + e) * M + m];
            PW[w * M + m] = f2bf(acc);
        } else {
            float part = 0.f;
            for (int m = tid; m < M; m += 256) {
                float h = b1[m];
                #pragma unroll
                for (int e = 0; e < E; ++e) h += wp_emb[w * E + e] * w1[e * M + m];
                part += fmaxf(h, 0.f) * w2[m];
            }
            red[tid] = part;
            __syncthreads();
            for (int s = 128; s > 0; s >>= 1) {
                if (tid < s) red[tid] += red[tid + s];
                __syncthreads();
            }
            if (tid == 0) wscore[w] = red[0] + b2[0];
        }
    }
}

// ------- merged scans: block0 = Dpre from ewa; block1 = offs+begs from hist -------
__global__ __launch_bounds__(256) void k_scans2(const float* __restrict__ ewa,
                                                float* __restrict__ Dpre,
                                                const int* __restrict__ hist,
                                                int* __restrict__ offs,
                                                int* __restrict__ begs) {
    __shared__ float shf[256];
    __shared__ int shi[256];
    int t = threadIdx.x;
    if (blockIdx.x == 0) {
        float v[16];
        float sum = 0.f;
        #pragma unroll
        for (int i = 0; i < 16; ++i) { v[i] = ewa[t * 16 + i]; sum += v[i]; }
        shf[t] = sum;
        __syncthreads();
        for (int off = 1; off < 256; off <<= 1) {
            float x = (t >= off) ? shf[t - off] : 0.f;
            __syncthreads();
            shf[t] += x;
            __syncthreads();
        }
        float run = shf[t] - sum;
        #pragma unroll
        for (int i = 0; i < 16; ++i) { run += v[i]; Dpre[t * 16 + i + 1] = run; }
        if (t == 0) Dpre[0] = 0.f;
    } else {
        int v[16];
        int sum = 0;
        #pragma unroll
        for (int i = 0; i < 16; ++i) { v[i] = hist[t * 16 + i]; sum += v[i]; }
        shi[t] = sum;
        __syncthreads();
        for (int off = 1; off < 256; off <<= 1) {
            int x = (t >= off) ? shi[t - off] : 0;
            __syncthreads();
            shi[t] += x;
            __syncthreads();
        }
        int run = shi[t] - sum;
        #pragma unroll
        for (int i = 0; i < 16; ++i) {
            offs[t * 16 + i] = run;
            begs[t * 16 + i] = run;
            run += v[i];
        }
        if (t == 255) begs[4096] = run;   // == NC
    }
}

// ---------------- sort-by-start: hist / scatter ----------------
__global__ __launch_bounds__(256) void k_hist(const int* __restrict__ starts,
                                              int* __restrict__ hist) {
    atomicAdd(&hist[starts[blockIdx.x * 256 + threadIdx.x]], 1);
}
__global__ __launch_bounds__(256) void k_scatter(const int* __restrict__ starts,
                                                 int* __restrict__ offs,
                                                 int* __restrict__ perm) {
    int c = blockIdx.x * 256 + threadIdx.x;
    int p = atomicAdd(&offs[starts[c]], 1);
    perm[p] = c;
}

// ---------------- MFMA projection: 128x192 tile, 8 waves, 2 BLOCKS/CU (r16) ----------
__global__ __launch_bounds__(512, 4) void k_proj_mfma(const unsigned short* __restrict__ docb,
                                                      const unsigned short* __restrict__ Bt,
                                                      const float* __restrict__ ewa,
                                                      unsigned short* __restrict__ Pse,
                                                      float* __restrict__ Sbuf,
                                                      float* __restrict__ T) {
    __shared__ unsigned short As[2][8192];   // [buf][mg:8][ks:2][g:4][ri:16][j:8] 32KB
    __shared__ unsigned short Bs[2][12288];  // [buf][cg:12][ks:2][g:4][ci:16][j:8] 48KB
    int tid = threadIdx.x;
    int bid = blockIdx.x;
    int xcd = bid & 7, rr0 = bid >> 3;              // rr0: 0..63
    int coltile = (xcd & 1) * 8 + (rr0 & 7);        // 0..15
    int rowtile = (xcd >> 1) * 8 + (rr0 >> 3);      // 0..31
    int col0 = coltile * 192;
    int row0 = rowtile * 128;
    int wv = tid >> 6, lane = tid & 63;
    int wr = wv >> 2, wc = wv & 3;                  // 2M x 4N waves; wave tile 64x48

    f32x4 acc[4][3];
    #pragma unroll
    for (int mi = 0; mi < 4; ++mi)
        #pragma unroll
        for (int ni = 0; ni < 3; ++ni) acc[mi][ni] = (f32x4){0.f, 0.f, 0.f, 0.f};

    #define STAGE(buf, k0)                                                            \
        {                                                                             \
            _Pragma("unroll")                                                         \
            for (int i = 0; i < 2; ++i) {                                             \
                int s = i * 512 + tid;                                                \
                int mg = s >> 7, ks = (s >> 6) & 1, g = (s >> 4) & 3, ri = s & 15;    \
                gload16(docb + (size_t)(row0 + mg * 16 + ri) * H + (k0) + ks * 32 + g * 8, \
                        (char*)As[buf] + s * 16);                                     \
            }                                                                         \
            _Pragma("unroll")                                                         \
            for (int i = 0; i < 3; ++i) {                                             \
                int s = i * 512 + tid;                                                \
                int cg = s >> 7, ks = (s >> 6) & 1, g = (s >> 4) & 3, ci = s & 15;    \
                gload16(Bt + (size_t)(col0 + cg * 16 + ci) * H + (k0) + ks * 32 + g * 8, \
                        (char*)Bs[buf] + s * 16);                                     \
            }                                                                         \
        }

    STAGE(0, 0);
    STAGE(1, 64);
    asm volatile("s_waitcnt vmcnt(5)" ::: "memory");  // tile 0 landed (tile 1 in flight)
    __builtin_amdgcn_s_barrier();

    #pragma unroll 1
    for (int t = 0; t < NKT; ++t) {
        int cur = t & 1;
        #pragma unroll
        for (int ks = 0; ks < 2; ++ks) {
            bf16x8 af[4], bfr[3];
            #pragma unroll
            for (int mi = 0; mi < 4; ++mi)
                af[mi] = *reinterpret_cast<const bf16x8*>(
                    (char*)As[cur] + (wr * 4 + mi) * 2048 + ks * 1024 + lane * 16);
            #pragma unroll
            for (int ni = 0; ni < 3; ++ni)
                bfr[ni] = *reinterpret_cast<const bf16x8*>(
                    (char*)Bs[cur] + (wc * 3 + ni) * 2048 + ks * 1024 + lane * 16);
            __builtin_amdgcn_s_setprio(1);
            #pragma unroll
            for (int mi = 0; mi < 4; ++mi)
                #pragma unroll
                for (int ni = 0; ni < 3; ++ni)
                    acc[mi][ni] = __builtin_amdgcn_mfma_f32_16x16x32_bf16(
                        af[mi], bfr[ni], acc[mi][ni], 0, 0, 0);
            __builtin_amdgcn_s_setprio(0);
        }
        if (t + 2 < NKT) {
            asm volatile("s_waitcnt lgkmcnt(0)" ::: "memory");  // all buf[cur] reads retired
            __builtin_amdgcn_sched_barrier(0);
            __builtin_amdgcn_s_barrier();                       // block-wide: buf[cur] free
            STAGE(cur, (t + 2) * 64);                           // overwrite buf[cur] w/ t+2
            asm volatile("s_waitcnt vmcnt(5)" ::: "memory");    // tile t+1 landed
            __builtin_amdgcn_s_barrier();                       // buf[cur^1] ready
        } else if (t + 2 == NKT) {
            asm volatile("s_waitcnt vmcnt(0)" ::: "memory");    // drain last tile
            __builtin_amdgcn_s_barrier();
        }
    }
    #undef STAGE

    int cr = (lane >> 4) * 4;
    int cc = lane & 15;
    #pragma unroll
    for (int mi = 0; mi < 4; ++mi) {
        #pragma unroll
        for (int ni = 0; ni < 3; ++ni) {
            int rrow = row0 + wr * 64 + mi * 16 + cr;
            int cabs = col0 + wc * 48 + ni * 16 + cc;
            int part = cabs >> 10;
            int cm = cabs & 1023;
            if (part < 2) {
                unsigned short* dst = Pse + (size_t)rrow * 2048 + part * 1024 + cm;
                #pragma unroll
                for (int j = 0; j < 4; ++j) dst[(size_t)j * 2048] = f2bf(acc[mi][ni][j]);
            } else {
                float* dst = Sbuf + (size_t)rrow * M + cm;
                #pragma unroll
                for (int j = 0; j < 4; ++j) dst[(size_t)j * M] = acc[mi][ni][j];
            }
        }
    }
    // ---- chunk totals T (scan1 fused): each wave's 64 rows = exactly one chunk ----
    {
        int chunk = (row0 >> 6) + wr;
        #pragma unroll
        for (int ni = 0; ni < 3; ++ni) {
            int cabs = col0 + wc * 48 + ni * 16 + cc;
            if (cabs >= 2048) {
                float psum = 0.f;
                #pragma unroll
                for (int mi = 0; mi < 4; ++mi) {
                    int rbase = row0 + wr * 64 + mi * 16 + cr;
                    #pragma unroll
                    for (int j = 0; j < 4; ++j)
                        psum += ewa[rbase + j] * acc[mi][ni][j];
                }
                psum += __shfl_down(psum, 16);
                psum += __shfl_down(psum, 32);
                if ((lane >> 4) == 0)
                    T[(size_t)chunk * M + (cabs - 2048)] = psum;
            }
        }
    }
}

// ---------------- scan phase 2: exclusive scan of chunk totals (reg-resident) ----------------
__global__ __launch_bounds__(256) void k_scan2(float* __restrict__ T) {
    int m = blockIdx.x * 256 + threadIdx.x;
    float v[NCH];
    #pragma unroll
    for (int c = 0; c < NCH; ++c) v[c] = T[c * M + m];
    float run = 0.f;
    #pragma unroll
    for (int c = 0; c < NCH; ++c) { float t = v[c]; T[c * M + m] = run; run += t; }
}

// ---------------- scan phase 3: in-place inclusive prefix over Sbuf ----------------
__global__ __launch_bounds__(256) void k_scan3(float* __restrict__ Sbuf,
                                               const float* __restrict__ ewa,
                                               const float* __restrict__ T) {
    int m = blockIdx.x * 256 + threadIdx.x;
    int c = blockIdx.y;
    __shared__ float ew[CHUNK];
    if (threadIdx.x < CHUNK) ew[threadIdx.x] = ewa[c * CHUNK + threadIdx.x];
    __syncthreads();
    float acc = T[c * M + m];
    float* base = Sbuf + (size_t)(c * CHUNK) * M + m;
    #pragma unroll 4
    for (int i = 0; i < CHUNK; ++i) {
        float* p = base + (size_t)i * M;
        acc += ew[i] * (*p);
        *p = acc;
    }
}

// ---------------- per-START candidate scoring: one block per start value ----------------
// r17: PW read as bf16 (per-candidate bytes 10KB -> 8KB; k_cand is L2-BW-bound).
__global__ __launch_bounds__(256) void k_cand(const unsigned short* __restrict__ Pse,
                                              const float* __restrict__ Sbuf,
                                              const unsigned short* __restrict__ PW,
                                              const float* __restrict__ Dpre,
                                              const float* __restrict__ wscore,
                                              const int* __restrict__ perm,
                                              const int* __restrict__ begs,
                                              const int* __restrict__ ends,
                                              const float* __restrict__ mlp2_w,
                                              const float* __restrict__ mlp2_b,
                                              float* __restrict__ out) {
    __shared__ __align__(16) unsigned short ps_l[1024];
    __shared__ __align__(16) float ss_l[1024];
    int bid = blockIdx.x;                           // 4096 blocks, %8==0 -> bijective
    int s = (bid & 7) * 512 + (bid >> 3);           // XCD-contiguous start ranges
    int tid = threadIdx.x;
    {
        ushort4 p4 = *reinterpret_cast<const ushort4*>(Pse + (size_t)s * 2048 + tid * 4);
        *reinterpret_cast<ushort4*>(ps_l + tid * 4) = p4;
        float4 s4 = (s > 0) ? *reinterpret_cast<const float4*>(Sbuf + (size_t)(s - 1) * M + tid * 4)
                            : make_float4(0.f, 0.f, 0.f, 0.f);
        *reinterpret_cast<float4*>(ss_l + tid * 4) = s4;
    }
    __syncthreads();
    int beg = begs[s], end = begs[s + 1];
    int wv = tid >> 6, lane = tid & 63;
    float dps = Dpre[s];
    // hoist candidate-invariant mlp2_w into registers
    float4 v00 = *reinterpret_cast<const float4*>(mlp2_w + lane * 8);
    float4 v01 = *reinterpret_cast<const float4*>(mlp2_w + lane * 8 + 4);
    float4 v10 = *reinterpret_cast<const float4*>(mlp2_w + lane * 8 + 512);
    float4 v11 = *reinterpret_cast<const float4*>(mlp2_w + lane * 8 + 516);

    for (int j = beg + wv; j < end; j += 4) {
        int c = perm[j];
        int e = ends[c];
        int wi = e - s;
        wi = wi > MSW - 1 ? MSW - 1 : wi;
        float inv = 1.f / (Dpre[e + 1] - dps);
        const unsigned short* pe = Pse + (size_t)e * 2048 + 1024;
        const float* se = Sbuf + (size_t)e * M;
        const unsigned short* pw = PW + (size_t)wi * M;

        float part = 0.f;
        #pragma unroll
        for (int q = 0; q < 2; ++q) {
            int m = lane * 8 + q * 512;
            u16x8 a8 = *reinterpret_cast<const u16x8*>(ps_l + m);
            u16x8 b8 = *reinterpret_cast<const u16x8*>(pe + m);
            u16x8 w8 = *reinterpret_cast<const u16x8*>(pw + m);
            float4 t0 = *reinterpret_cast<const float4*>(se + m);
            float4 t1 = *reinterpret_cast<const float4*>(se + m + 4);
            float4 u0 = *reinterpret_cast<const float4*>(ss_l + m);
            float4 u1 = *reinterpret_cast<const float4*>(ss_l + m + 4);
            float4 v0 = q ? v10 : v00;
            float4 v1 = q ? v11 : v01;
            float x;
            x = bf2f(a8[0]) + bf2f(b8[0]) + bf2f(w8[0]) + (t0.x - u0.x) * inv; part += fmaxf(x, 0.f) * v0.x;
            x = bf2f(a8[1]) + bf2f(b8[1]) + bf2f(w8[1]) + (t0.y - u0.y) * inv; part += fmaxf(x, 0.f) * v0.y;
            x = bf2f(a8[2]) + bf2f(b8[2]) + bf2f(w8[2]) + (t0.z - u0.z) * inv; part += fmaxf(x, 0.f) * v0.z;
            x = bf2f(a8[3]) + bf2f(b8[3]) + bf2f(w8[3]) + (t0.w - u0.w) * inv; part += fmaxf(x, 0.f) * v0.w;
            x = bf2f(a8[4]) + bf2f(b8[4]) + bf2f(w8[4]) + (t1.x - u1.x) * inv; part += fmaxf(x, 0.f) * v1.x;
            x = bf2f(a8[5]) + bf2f(b8[5]) + bf2f(w8[5]) + (t1.y - u1.y) * inv; part += fmaxf(x, 0.f) * v1.y;
            x = bf2f(a8[6]) + bf2f(b8[6]) + bf2f(w8[6]) + (t1.z - u1.z) * inv; part += fmaxf(x, 0.f) * v1.z;
            x = bf2f(a8[7]) + bf2f(b8[7]) + bf2f(w8[7]) + (t1.w - u1.w) * inv; part += fmaxf(x, 0.f) * v1.w;
        }
        #pragma unroll
        for (int off = 32; off > 0; off >>= 1) part += __shfl_down(part, off);
        if (lane == 0) out[c] = part + mlp2_b[0] + wscore[wi];
    }
}

extern "C" void kernel_launch(void* const* d_in, const int* in_sizes, int n_in,
                              void* d_out, int out_size, void* d_ws, size_t ws_size,
                              hipStream_t stream) {
    const float* encoded_doc = (const float*)d_in[0];
    const int*   cand_starts = (const int*)d_in[1];
    const int*   cand_ends   = (const int*)d_in[2];
    const float* width_emb   = (const float*)d_in[3];
    const float* width_prior = (const float*)d_in[4];
    const float* attn_w      = (const float*)d_in[5];
    const float* attn_b      = (const float*)d_in[6];
    const float* mlp1_w      = (const float*)d_in[7];
    const float* mlp1_b      = (const float*)d_in[8];
    const float* mlp2_w      = (const float*)d_in[9];
    const float* mlp2_b      = (const float*)d_in[10];
    const float* wmlp1_w     = (const float*)d_in[11];
    const float* wmlp1_b     = (const float*)d_in[12];
    const float* wmlp2_w     = (const float*)d_in[13];
    const float* wmlp2_b     = (const float*)d_in[14];
    float* out = (float*)d_out;

    // workspace layout (float units from base; all large blocks 16B-aligned)
    float* Sbuf   = (float*)d_ws;                      // NW*1024
    float* T      = Sbuf + (size_t)NW * M;             // NCH*M = 65536
    unsigned short* PW = (unsigned short*)(T + NCH * M);        // 30*1024 bf16 (slot 30*1024 f32)
    float* ewa    = (float*)PW + MSW * M;              // 4096 (PW slot kept f32-sized)
    float* Dpre   = ewa + NW;                          // 4160
    float* wscore = Dpre + 4160;                       // 64
    unsigned short* Pse  = (unsigned short*)(wscore + 64);      // NW*2048 bf16
    unsigned short* docb = Pse + (size_t)NW * 2048;             // NW*H bf16
    unsigned short* Btb  = docb + (size_t)NW * H;               // 3072*H bf16
    int* hist = (int*)(Btb + (size_t)3072 * H);        // 4096
    int* offs = hist + 4096;                           // 4096
    int* begs = offs + 4096;                           // 4097 (pad 4112)
    int* perm = begs + 4112;                           // NC

    k_prep<<<3478, 256, 0, stream>>>(encoded_doc, attn_w, attn_b, docb, ewa, hist,
                                     mlp1_w, Btb, width_emb, mlp1_b, PW,
                                     width_prior, wmlp1_w, wmlp1_b, wmlp2_w, wmlp2_b, wscore);
    k_hist<<<NC / 256, 256, 0, stream>>>(cand_starts, hist);
    k_scans2<<<2, 256, 0, stream>>>(ewa, Dpre, hist, offs, begs);
    k_scatter<<<NC / 256, 256, 0, stream>>>(cand_starts, offs, perm);
    k_proj_mfma<<<512, 512, 0, stream>>>(docb, Btb, ewa, Pse, Sbuf, T);
    k_scan2<<<M / 256, 256, 0, stream>>>(T);
    k_scan3<<<dim3(M / 256, NCH), 256, 0, stream>>>(Sbuf, ewa, T);
    k_cand<<<4096, 256, 0, stream>>>(Pse, Sbuf, PW, Dpre, wscore, perm, begs,
                                     cand_ends, mlp2_w, mlp2_b, out);
}